// Round 9
// baseline (5260.691 us; speedup 1.0000x reference)
//
#include <hip/hip_runtime.h>

// ---------------- problem constants ----------------
#define B_ 32
#define S_ 64
#define C_ 512
#define E_ 256
#define H_ 512
#define V_ 32000
#define T_ 32
#define NBLK 256       // grid blocks (persistent kernel)
#define NTHR 512       // threads per block (8 waves)
#define ND 250         // scan blocks (250*128 = 32000); blocks 250..255 = attention
#define START_TOK 1
#define DELTA 0.05f    // candidate window (bf16 logit err sigma ~6e-4)
#define BH (B_ * H_)

// ---------------- workspace layout (float offsets) ----------------
// counters/flags (ints): attC@0 attF@256+g*32, h0C@1024 h0F@1280+g*32,
//                        h1C@2048 h1F@2304+g*32, scC@3072 scF@3328+g*32
#define OFF_CNT  0          // 4096
#define OFF_CS   4096       // cscore[32][64] = 2048
#define OFF_LSEA 6144       // lse[32 t][32 b] = 1024 (written by lse_all)
#define OFF_GMAX 7168       // u64 gmax[1024], strided *8 (64B apart) = 16384 f
#define OFF_CCNT 23552      // int ccnt[1024], strided *32 = 32768
#define OFF_CLST 56320      // int clist[1024][64] = 65536
#define OFF_LSM  121856     // float [1024][256] = 262144 (plain stores)
#define OFF_LSS  384000     // float [1024][256] = 262144
#define OFF_ATT  646144     // attend replicas [8][32][512] = 131072
#define OFF_H0R  777216     // h0 replicas [8][2][32][512] = 262144
#define OFF_H1R  1039360    // h1 fp32 replicas [8][2][32][512] = 262144
#define OFF_H1B8 1301504    // h1 bf16 replicas [8][32][512] ushort = 65536 f
#define OFF_H1BF 1367040    // history ushort[1024][512] = 262144 f (plain)
#define OFF_WOBF 1629184    // ushort[32000][512] bf16 Wo = 8192000 f
#define WS_FLOATS 9821184   // ~39.3 MB

typedef unsigned long long ull;
typedef __attribute__((ext_vector_type(8))) short bf16x8;
typedef __attribute__((ext_vector_type(4))) float f32x4;

struct Params {
  const float* ctx; const float* embed; const float* Wa;
  const float* Wih0; const float* Whh0; const float* bih0; const float* bhh0;
  const float* Wih1; const float* Whh1; const float* bih1; const float* bhh1;
  const float* Wo; const float* bo;
  float* ws; float* out;
};

__device__ __forceinline__ float sigf(float x) { return 1.0f / (1.0f + expf(-x)); }

__device__ __forceinline__ unsigned short f2bf(float f) {  // RNE f32->bf16
  unsigned u = __builtin_bit_cast(unsigned, f);
  unsigned r = (u + 0x7FFFu + ((u >> 16) & 1u)) >> 16;
  return (unsigned short)r;
}

__device__ __forceinline__ void lse_merge(float& m, float& s, float m2, float s2) {
  float M = fmaxf(m, m2);
  s = s * expf(m - M) + s2 * expf(m2 - M);
  m = M;
}

// ---- coherent (L2-bypass) access for mutable cross-block data ----
__device__ __forceinline__ float ld_cf(const float* p) {
  return __hip_atomic_load(p, __ATOMIC_RELAXED, __HIP_MEMORY_SCOPE_AGENT);
}
__device__ __forceinline__ void st_cf(float* p, float v) {
  __hip_atomic_store(p, v, __ATOMIC_RELAXED, __HIP_MEMORY_SCOPE_AGENT);
}
__device__ __forceinline__ int ld_ci(const int* p) {
  return __hip_atomic_load(p, __ATOMIC_RELAXED, __HIP_MEMORY_SCOPE_AGENT);
}
__device__ __forceinline__ void st_ci(int* p, int v) {
  __hip_atomic_store(p, v, __ATOMIC_RELAXED, __HIP_MEMORY_SCOPE_AGENT);
}
__device__ __forceinline__ unsigned ld_cu(const unsigned* p) {
  return __hip_atomic_load(p, __ATOMIC_RELAXED, __HIP_MEMORY_SCOPE_AGENT);
}
__device__ __forceinline__ void st_cu(unsigned* p, unsigned v) {
  __hip_atomic_store(p, v, __ATOMIC_RELAXED, __HIP_MEMORY_SCOPE_AGENT);
}

// arrive/wait counter pair: producers add and continue; last arriver broadcasts
// epoch to 8 spread flag lines; consumers poll their line only.
__device__ __forceinline__ void arrive(unsigned* ws, int cOff, int fOff,
                                       unsigned target, unsigned epoch) {
  unsigned old = __hip_atomic_fetch_add(ws + cOff, 1u, __ATOMIC_RELAXED,
                                        __HIP_MEMORY_SCOPE_AGENT);
  if (old == target - 1u) {
#pragma unroll
    for (int g = 0; g < 8; ++g) st_cu(ws + fOff + g * 32, epoch);
  }
}
__device__ __forceinline__ void waitf(const unsigned* flag, unsigned epoch) {
  while (ld_cu(flag) < epoch) __builtin_amdgcn_s_sleep(2);
}

// argmax packing: monotone f32->u32, tie-break smallest idx via ~idx
__device__ __forceinline__ ull packvi(float v, int idx) {
  unsigned u = __builtin_bit_cast(unsigned, v);
  unsigned m = (u & 0x80000000u) ? ~u : (u | 0x80000000u);
  return ((ull)m << 32) | (ull)(~(unsigned)idx);
}
__device__ __forceinline__ float unpackv(ull g) {
  unsigned m = (unsigned)(g >> 32);
  unsigned raw = (m & 0x80000000u) ? (m & 0x7fffffffu) : ~m;
  return __builtin_bit_cast(float, raw);
}

// ---------------- prologue kernels ----------------
__global__ void __launch_bounds__(256) zero_k(float* wsf) {
  const unsigned i = blockIdx.x * 256u + threadIdx.x;
  if (i < 4096u) ((unsigned*)wsf)[i] = 0u;
  if (i < 49152u) wsf[OFF_GMAX + i] = 0.0f;        // gmax + ccnt
  if (i < 262144u) { wsf[OFF_H0R + i] = 0.0f; wsf[OFF_H1R + i] = 0.0f; }
}

__global__ void __launch_bounds__(256) cscore_k(const float* __restrict__ ctx,
                                                const float* __restrict__ Wa,
                                                const float* __restrict__ ba,
                                                float* __restrict__ wsf) {
  const int b = blockIdx.x;
  const int s = threadIdx.x >> 2, q = threadIdx.x & 3;
  const float* cp = ctx + ((size_t)b * S_ + s) * C_ + q * 128;
  const float* wp = Wa + H_ + q * 128;     // context half of Wa
  float acc = 0.f;
#pragma unroll 8
  for (int k = 0; k < 128; ++k) acc = fmaf(cp[k], wp[k], acc);
  acc += __shfl_xor(acc, 1);
  acc += __shfl_xor(acc, 2);
  if (q == 0) wsf[OFF_CS + b * S_ + s] = acc + ba[0];
}

__global__ void __launch_bounds__(256) cvt_wobf(const float* __restrict__ wo,
                                                unsigned short* __restrict__ dst) {
  const size_t i = ((size_t)blockIdx.x * 256u + threadIdx.x) * 4;
  float4 v = *(const float4*)(wo + i);
  ushort4 o;
  o.x = f2bf(v.x); o.y = f2bf(v.y); o.z = f2bf(v.z); o.w = f2bf(v.w);
  *(ushort4*)(dst + i) = o;
}

// attention batch split over 6 blocks
__device__ __constant__ int AST[7] = {0, 6, 12, 17, 22, 27, 32};

// ---------------- main persistent kernel ----------------
__global__ void __launch_bounds__(NTHR) mtad_main(Params p) {
  float* wsf = p.ws;
  unsigned* cw = (unsigned*)p.ws;
  unsigned short* h1bf = (unsigned short*)(wsf + OFF_H1BF);
  const unsigned short* wobf = (const unsigned short*)(wsf + OFF_WOBF);
  const int bk = blockIdx.x, tx = threadIdx.x;
  const int ug = bk & 31, bg = bk >> 5, b4 = bg * 4;
  const int rep = bk & 7;

  __shared__ __align__(16) unsigned char woL[131072];  // 128 KB bf16 Wo rows (swizzled)
  __shared__ __align__(16) char SMEM[28672];           // phase-dependent blob
  __shared__ float wlds[64];
  __shared__ float hout[64];
  __shared__ int   stok4[4];
  __shared__ float shsS;
  __shared__ float scrV[8];
  __shared__ int   scrI[8];

  // ---------- prologue ----------
  if (bk < ND) {     // fill woL (swizzled) from WOBF
    const unsigned short* src = wobf + (size_t)bk * 128 * H_;
    for (int c = tx; c < 8192; c += NTHR) {
      const int row = c >> 6, cc = c & 63;
      uint4 v = *(const uint4*)(src + (size_t)row * H_ + cc * 8);
      *(uint4*)&woL[row * 1024 + ((cc * 16) ^ ((row & 7) << 4))] = v;
    }
  } else {           // attention blocks: attend(0) from cscore only (h1=0)
    const int q = bk - ND;
    for (int b = AST[q]; b < AST[q + 1]; ++b) {
      if (tx < S_) {
        float sc = tanhf(wsf[OFF_CS + b * S_ + tx]);
        float e = expf(sc); float sum = e;
#pragma unroll
        for (int d = 1; d < 64; d <<= 1) sum += __shfl_xor(sum, d);
        float w = e / sum; wlds[tx] = w;
        p.out[(size_t)B_ * T_ * V_ + ((size_t)b * T_ + 0) * S_ + tx] = w;
      }
      __syncthreads();
      float a0 = 0.f;
      const float* cb = p.ctx + (size_t)b * S_ * C_ + tx;
#pragma unroll 8
      for (int s2 = 0; s2 < S_; ++s2) a0 = fmaf(wlds[s2], cb[(size_t)s2 * C_], a0);
#pragma unroll
      for (int r = 0; r < 8; ++r)
        st_cf(wsf + OFF_ATT + (size_t)r * 16384 + (size_t)b * H_ + tx, a0);
      __syncthreads();
    }
    asm volatile("s_waitcnt vmcnt(0)" ::: "memory");
    __syncthreads();
    if (tx == 0) arrive(cw, 0, 256, 6u, 1u);          // attcnt -> 6, flag epoch 1
  }

  for (int t = 0; t < T_; ++t) {
    const unsigned ut = (unsigned)t;
    const int par = t & 1;
    // =================== GRU layer 0 (all blocks) ===================
    {
      float* sacts = (float*)SMEM;            // [4][768]
      float* sh0l  = (float*)(SMEM + 12288);  // [4][512]
      float* sh1r  = (float*)(SMEM + 20480);  // [4][512] h1_prev (refine + GRU1)
      if (tx == 0) waitf(cw + 256 + rep * 32, ut + 1u);   // attend(t) ready
      __syncthreads();
      {  // stage attend, h0prev, h1prev from replicas
        const ull* pA = (const ull*)(wsf + OFF_ATT) + (size_t)rep * 8192;
        const ull* pH0 = (const ull*)(wsf + OFF_H0R) + ((size_t)rep * 2 + par) * 8192;
        const ull* pH1 = (const ull*)(wsf + OFF_H1R) + ((size_t)rep * 2 + par) * 8192;
        ull va[2], vh[2], vr[2];
#pragma unroll
        for (int k = 0; k < 2; ++k) {
          const int iu = k * NTHR + tx;
          const int bb = iu >> 8, cc = iu & 255;
          const ull* a1 = pA + (size_t)(b4 + bb) * 256 + cc;
          const ull* a2 = pH0 + (size_t)(b4 + bb) * 256 + cc;
          const ull* a3 = pH1 + (size_t)(b4 + bb) * 256 + cc;
          asm volatile("global_load_dwordx2 %0, %1, off sc0 sc1" : "=v"(va[k]) : "v"(a1));
          asm volatile("global_load_dwordx2 %0, %1, off sc0 sc1" : "=v"(vh[k]) : "v"(a2));
          asm volatile("global_load_dwordx2 %0, %1, off sc0 sc1" : "=v"(vr[k]) : "v"(a3));
        }
        asm volatile("s_waitcnt vmcnt(0)" ::: "memory");
#pragma unroll
        for (int k = 0; k < 2; ++k) {
          const int iu = k * NTHR + tx;
          const int bb = iu >> 8, cc = iu & 255;
          *(ull*)&sacts[bb * 768 + 256 + cc * 2] = va[k];
          *(ull*)&sh0l[bb * 512 + cc * 2] = vh[k];
          *(ull*)&sh1r[bb * 512 + cc * 2] = vr[k];
        }
      }
      __syncthreads();
      const int u = tx >> 5, l = tx & 31;
      const int j = ug * 16 + u;
      float red[16];
#pragma unroll
      for (int q = 0; q < 16; ++q) red[q] = 0.f;
      // partial gates: attend x-part (c=2..5) + hidden part (c=0..3)
#pragma unroll
      for (int g = 0; g < 3; ++g) {
        const float4* wx = (const float4*)(p.Wih0 + (size_t)(g * H_ + j) * 768);
        float* dx = (g < 2) ? &red[g * 4] : &red[8];
#pragma unroll
        for (int c = 2; c < 6; ++c) {
          float4 w = wx[l + 32 * c];
#pragma unroll
          for (int b2 = 0; b2 < 4; ++b2) {
            const float* a = &sacts[b2 * 768 + 4 * l + 128 * c];
            dx[b2] = fmaf(w.x, a[0], dx[b2]); dx[b2] = fmaf(w.y, a[1], dx[b2]);
            dx[b2] = fmaf(w.z, a[2], dx[b2]); dx[b2] = fmaf(w.w, a[3], dx[b2]);
          }
        }
        const float4* wh = (const float4*)(p.Whh0 + (size_t)(g * H_ + j) * H_);
        float* dh = (g < 2) ? &red[g * 4] : &red[12];
#pragma unroll
        for (int c = 0; c < 4; ++c) {
          float4 w = wh[l + 32 * c];
#pragma unroll
          for (int b2 = 0; b2 < 4; ++b2) {
            const float* a = &sh0l[b2 * 512 + 4 * l + 128 * c];
            dh[b2] = fmaf(w.x, a[0], dh[b2]); dh[b2] = fmaf(w.y, a[1], dh[b2]);
            dh[b2] = fmaf(w.z, a[2], dh[b2]); dh[b2] = fmaf(w.w, a[3], dh[b2]);
          }
        }
      }
      // -------- token: refine candidates from scan(t-1) (redundant/block) -----
      if (t > 0) {
        if (tx == 0) waitf(cw + 3328 + rep * 32, ut);     // scan(t-1) done
        __syncthreads();
        const int w = tx >> 6, lane = tx & 63;
        const int lb = w >> 1, ws2 = w & 1, b = b4 + lb;
        const int cbase = (t - 1) * 32 + b;
        int nc = 0;
        if (lane == 0) nc = ld_ci((const int*)wsf + OFF_CCNT + (size_t)cbase * 32);
        nc = __builtin_amdgcn_readfirstlane(nc);
        if (nc > 64) nc = 64;
        float bV = -3.0e38f; int bI = 0x7fffffff;
        for (int c = ws2; c < nc; c += 2) {
          int idx = 0;
          if (lane == 0) idx = ld_ci((const int*)wsf + OFF_CLST + (size_t)cbase * 64 + c);
          idx = __builtin_amdgcn_readfirstlane(idx);
          const float* wr = p.Wo + (size_t)idx * H_ + lane * 8;
          const float* hr = sh1r + lb * 512 + lane * 8;
          float a = 0.f;
#pragma unroll
          for (int e = 0; e < 8; ++e) a = fmaf(hr[e], wr[e], a);
#pragma unroll
          for (int d = 1; d < 64; d <<= 1) a += __shfl_xor(a, d);
          a += p.bo[idx];
          if (a > bV || (a == bV && idx < bI)) { bV = a; bI = idx; }
        }
        if (lane == 0) { scrV[w] = bV; scrI[w] = bI; }
        __syncthreads();
        if (tx < 4) {
          float v0 = scrV[tx * 2], v1 = scrV[tx * 2 + 1];
          int i0 = scrI[tx * 2], i1 = scrI[tx * 2 + 1];
          stok4[tx] = (v1 > v0 || (v1 == v0 && i1 < i0)) ? i1 : i0;
        }
      } else {
        if (tx < 4) stok4[tx] = START_TOK;
      }
      __syncthreads();
      // embed stage + embed gates (c=0,1)
#pragma unroll
      for (int k = 0; k < 2; ++k) {
        const int idx = k * NTHR + tx;
        const int bb = idx >> 8, e = idx & 255;
        sacts[bb * 768 + e] = p.embed[(size_t)stok4[bb] * E_ + e];
      }
      __syncthreads();
#pragma unroll
      for (int g = 0; g < 3; ++g) {
        const float4* wx = (const float4*)(p.Wih0 + (size_t)(g * H_ + j) * 768);
        float* dx = (g < 2) ? &red[g * 4] : &red[8];
#pragma unroll
        for (int c = 0; c < 2; ++c) {
          float4 w = wx[l + 32 * c];
#pragma unroll
          for (int b2 = 0; b2 < 4; ++b2) {
            const float* a = &sacts[b2 * 768 + 4 * l + 128 * c];
            dx[b2] = fmaf(w.x, a[0], dx[b2]); dx[b2] = fmaf(w.y, a[1], dx[b2]);
            dx[b2] = fmaf(w.z, a[2], dx[b2]); dx[b2] = fmaf(w.w, a[3], dx[b2]);
          }
        }
      }
#pragma unroll
      for (int d = 1; d < 32; d <<= 1)
#pragma unroll
        for (int q = 0; q < 16; ++q) red[q] += __shfl_xor(red[q], d);
      if (l < 4) {
        const float rr = sigf(red[l] + p.bih0[j] + p.bhh0[j]);
        const float zz = sigf(red[4 + l] + p.bih0[H_ + j] + p.bhh0[H_ + j]);
        const float nn = tanhf(red[8 + l] + p.bih0[2 * H_ + j] +
                               rr * (red[12 + l] + p.bhh0[2 * H_ + j]));
        const float hp = sh0l[l * 512 + j];
        const float h0new = (1.f - zz) * nn + zz * hp;
#pragma unroll
        for (int r = 0; r < 8; ++r)
          st_cf(wsf + OFF_H0R + ((size_t)(r * 2 + (1 - par))) * BH +
                (size_t)(b4 + l) * H_ + j, h0new);
      }
      asm volatile("s_waitcnt vmcnt(0)" ::: "memory");
      __syncthreads();
      if (tx == 0) arrive(cw, 1024, 1280, 256u * (ut + 1u), ut + 1u);   // h0cnt
    }
    // =================== GRU layer 1 (all blocks) ===================
    {
      float* sx = (float*)SMEM;                 // [4][512] h0_new
      float* sh = (float*)(SMEM + 20480);       // h1_prev (kept from GRU0 stage)
      if (tx == 0) waitf(cw + 1280 + rep * 32, ut + 1u);
      __syncthreads();
      {
        const ull* pX = (const ull*)(wsf + OFF_H0R) + ((size_t)rep * 2 + (1 - par)) * 8192;
        ull vx[2];
#pragma unroll
        for (int k = 0; k < 2; ++k) {
          const int iu = k * NTHR + tx;
          const int bb = iu >> 8, cc = iu & 255;
          const ull* a1 = pX + (size_t)(b4 + bb) * 256 + cc;
          asm volatile("global_load_dwordx2 %0, %1, off sc0 sc1" : "=v"(vx[k]) : "v"(a1));
        }
        asm volatile("s_waitcnt vmcnt(0)" ::: "memory");
#pragma unroll
        for (int k = 0; k < 2; ++k) {
          const int iu = k * NTHR + tx;
          const int bb = iu >> 8, cc = iu & 255;
          *(ull*)&sx[bb * 512 + cc * 2] = vx[k];
        }
      }
      __syncthreads();
      const int u = tx >> 5, l = tx & 31;
      const int j = ug * 16 + u;
      float red[16];
#pragma unroll
      for (int q = 0; q < 16; ++q) red[q] = 0.f;
#pragma unroll
      for (int g = 0; g < 3; ++g) {
        const float4* wx = (const float4*)(p.Wih1 + (size_t)(g * H_ + j) * H_);
        float* dx = (g < 2) ? &red[g * 4] : &red[8];
#pragma unroll
        for (int c = 0; c < 4; ++c) {
          float4 w = wx[l + 32 * c];
#pragma unroll
          for (int b2 = 0; b2 < 4; ++b2) {
            const float* a = &sx[b2 * 512 + 4 * l + 128 * c];
            dx[b2] = fmaf(w.x, a[0], dx[b2]); dx[b2] = fmaf(w.y, a[1], dx[b2]);
            dx[b2] = fmaf(w.z, a[2], dx[b2]); dx[b2] = fmaf(w.w, a[3], dx[b2]);
          }
        }
        const float4* wh = (const float4*)(p.Whh1 + (size_t)(g * H_ + j) * H_);
        float* dh = (g < 2) ? &red[g * 4] : &red[12];
#pragma unroll
        for (int c = 0; c < 4; ++c) {
          float4 w = wh[l + 32 * c];
#pragma unroll
          for (int b2 = 0; b2 < 4; ++b2) {
            const float* a = &sh[b2 * 512 + 4 * l + 128 * c];
            dh[b2] = fmaf(w.x, a[0], dh[b2]); dh[b2] = fmaf(w.y, a[1], dh[b2]);
            dh[b2] = fmaf(w.z, a[2], dh[b2]); dh[b2] = fmaf(w.w, a[3], dh[b2]);
          }
        }
      }
#pragma unroll
      for (int d = 1; d < 32; d <<= 1)
#pragma unroll
        for (int q = 0; q < 16; ++q) red[q] += __shfl_xor(red[q], d);
      if (l < 4) {
        const float rr = sigf(red[l] + p.bih1[j] + p.bhh1[j]);
        const float zz = sigf(red[4 + l] + p.bih1[H_ + j] + p.bhh1[H_ + j]);
        const float nn = tanhf(red[8 + l] + p.bih1[2 * H_ + j] +
                               rr * (red[12 + l] + p.bhh1[2 * H_ + j]));
        const float hp = sh[l * 512 + j];
        const float hnew = (1.f - zz) * nn + zz * hp;
#pragma unroll
        for (int r = 0; r < 8; ++r)
          st_cf(wsf + OFF_H1R + ((size_t)(r * 2 + (1 - par))) * BH +
                (size_t)(b4 + l) * H_ + j, hnew);
        hout[u * 4 + l] = hnew;
      }
      __syncthreads();
      if (tx < 32) {   // bf16 pack (2 units / dword): 8 replicas + history
        const int b2 = tx & 3, pp = tx >> 2;
        const float h0v = hout[(pp * 2) * 4 + b2];
        const float h1v = hout[(pp * 2 + 1) * 4 + b2];
        const unsigned pk = (unsigned)f2bf(h0v) | ((unsigned)f2bf(h1v) << 16);
        int* h1b8i = (int*)(wsf + OFF_H1B8);
#pragma unroll
        for (int r = 0; r < 8; ++r)
          st_ci(h1b8i + (size_t)r * 8192 + (size_t)(b4 + b2) * 256 + ug * 8 + pp, (int)pk);
        *(int*)(h1bf + ((size_t)t * B_ + b4 + b2) * H_ + ug * 16 + pp * 2) = (int)pk; // plain
      }
      asm volatile("s_waitcnt vmcnt(0)" ::: "memory");
      __syncthreads();
      if (tx == 0) arrive(cw, 2048, 2304, 256u * (ut + 1u), ut + 1u);   // h1cnt
    }
    // ======= tail: vocab scan (bk<ND) || attention(t+1) (bk>=ND) =======
    if (bk < ND) {
      const int v0 = bk * 128;
      char* stgB = SMEM;                               // [16][1024B] swizzled bf16 h1
      float (*scrF)[16][4] = (float(*)[16][4])(SMEM + 16384);
      int (*scrI2)[16][2] = (int(*)[16][2])(SMEM + 18432);
      if (tx == 0) waitf(cw + 2304 + rep * 32, ut + 1u);
      __syncthreads();
      const int w = tx >> 6, l = tx & 63, lr = l & 15, lq = l >> 4;
      for (int bt = 0; bt < 2; ++bt) {
        {  // stage h1 bf16 btile from replica (swizzled LDS write)
          const ull* src = (const ull*)(wsf + OFF_H1B8) + (size_t)rep * 4096 +
                           (size_t)bt * 2048;
          ull vv[4];
#pragma unroll
          for (int e = 0; e < 4; ++e) {
            const ull* ap = src + (size_t)tx * 4 + e;
            asm volatile("global_load_dwordx2 %0, %1, off sc0 sc1" : "=v"(vv[e]) : "v"(ap));
          }
          asm volatile("s_waitcnt vmcnt(0)" ::: "memory");
#pragma unroll
          for (int e = 0; e < 4; ++e) {
            const int uu = tx * 4 + e;                 // ull index 0..2047
            const int row = uu >> 7, wb = (uu & 127) * 8;
            const int base = wb & ~15, half = wb & 8;
            *(ull*)&stgB[row * 1024 + ((base ^ ((row & 7) << 4)) | half)] = vv[e];
          }
        }
        __syncthreads();
        f32x4 acc = {0.f, 0.f, 0.f, 0.f};
        const int vr = w * 16 + lr;
#pragma unroll
        for (int kc = 0; kc < 16; ++kc) {
          const int koff = kc * 64 + lq * 16;
          bf16x8 a = *(const bf16x8*)&stgB[lr * 1024 + (koff ^ ((lr & 7) << 4))];
          bf16x8 bf = *(const bf16x8*)&woL[vr * 1024 + (koff ^ ((lr & 7) << 4))];
          acc = __builtin_amdgcn_mfma_f32_16x16x32_bf16(a, bf, acc, 0, 0, 0);
        }
        const float bov = p.bo[v0 + vr];
#pragma unroll
        for (int r = 0; r < 4; ++r) {
          float v1 = acc[r] + bov, v2 = -3.0e38f;
          int i1 = v0 + vr, i2 = 0x7fffffff;
          float m = v1, s = 1.0f;
#pragma unroll
          for (int d = 1; d < 16; d <<= 1) {
            float w1 = __shfl_xor(v1, d); int j1 = __shfl_xor(i1, d);
            float w2 = __shfl_xor(v2, d); int j2 = __shfl_xor(i2, d);
            float m2 = __shfl_xor(m, d);  float s2 = __shfl_xor(s, d);
            if (w1 > v1 || (w1 == v1 && j1 < i1)) { v2 = v1; i2 = i1; v1 = w1; i1 = j1; }
            else if (w1 > v2 || (w1 == v2 && j1 < i2)) { v2 = w1; i2 = j1; }
            if (w2 > v2 || (w2 == v2 && j2 < i2)) {
              if (w2 > v1 || (w2 == v1 && j2 < i1)) { v2 = v1; i2 = i1; v1 = w2; i1 = j2; }
              else { v2 = w2; i2 = j2; }
            }
            lse_merge(m, s, m2, s2);
          }
          if (lr == 0) {
            const int bb = lq * 4 + r;
            scrF[w][bb][0] = v1; scrF[w][bb][1] = v2;
            scrF[w][bb][2] = m;  scrF[w][bb][3] = s;
            scrI2[w][bb][0] = i1; scrI2[w][bb][1] = i2;
          }
        }
        __syncthreads();
        if (tx < 16) {   // combine 8 waves; publish lse partials + argmax cands
          float v1 = scrF[0][tx][0], v2 = scrF[0][tx][1];
          float m = scrF[0][tx][2], s = scrF[0][tx][3];
          int i1 = scrI2[0][tx][0], i2 = scrI2[0][tx][1];
#pragma unroll
          for (int ww = 1; ww < 8; ++ww) {
            float w1 = scrF[ww][tx][0]; int j1 = scrI2[ww][tx][0];
            float w2 = scrF[ww][tx][1]; int j2 = scrI2[ww][tx][1];
            if (w1 > v1 || (w1 == v1 && j1 < i1)) { v2 = v1; i2 = i1; v1 = w1; i1 = j1; }
            else if (w1 > v2 || (w1 == v2 && j1 < i2)) { v2 = w1; i2 = j1; }
            if (w2 > v2 || (w2 == v2 && j2 < i2)) {
              if (w2 > v1 || (w2 == v1 && j2 < i1)) { v2 = v1; i2 = i1; v1 = w2; i1 = j2; }
              else { v2 = w2; i2 = j2; }
            }
            lse_merge(m, s, scrF[ww][tx][2], scrF[ww][tx][3]);
          }
          const int b = bt * 16 + tx;
          const size_t cb = (size_t)(t * 32 + b);
          wsf[OFF_LSM + cb * 256 + bk] = m;     // plain stores (post-kernel reduce)
          wsf[OFF_LSS + cb * 256 + bk] = s;
          ull pk1 = packvi(v1, i1);
          ull* gm = (ull*)(wsf + OFF_GMAX) + cb * 8;
          ull old = __hip_atomic_fetch_max(gm, pk1, __ATOMIC_RELAXED,
                                           __HIP_MEMORY_SCOPE_AGENT);
          ull cur = old > pk1 ? old : pk1;
          float curv = unpackv(cur);
          int* ccp = (int*)wsf + OFF_CCNT + cb * 32;
          int* clp = (int*)wsf + OFF_CLST + cb * 64;
          if (v1 >= curv - DELTA) {
            int k = __hip_atomic_fetch_add(ccp, 1, __ATOMIC_RELAXED,
                                           __HIP_MEMORY_SCOPE_AGENT);
            if (k < 64) st_ci(clp + k, i1);
          }
          if (i2 != 0x7fffffff && v2 >= curv - DELTA) {
            int k = __hip_atomic_fetch_add(ccp, 1, __ATOMIC_RELAXED,
                                           __HIP_MEMORY_SCOPE_AGENT);
            if (k < 64) st_ci(clp + k, i2);
          }
        }
        __syncthreads();
      }
      asm volatile("s_waitcnt vmcnt(0)" ::: "memory");
      __syncthreads();
      if (tx == 0) arrive(cw, 3072, 3328, 250u * (ut + 1u), ut + 1u);   // scancnt
    } else {
      if (tx == 0) waitf(cw + 2304 + rep * 32, ut + 1u);
      __syncthreads();
      if (t < T_ - 1) {                   // attention for step t+1
        const int q = bk - ND;
        float* rv = (float*)SMEM;                 // [512]
        float* sh1a = (float*)(SMEM + 2048);      // [512]
        for (int b = AST[q]; b < AST[q + 1]; ++b) {
          sh1a[tx] = ld_cf(wsf + OFF_H1R + ((size_t)rep * 2 + (1 - par)) * BH +
                           (size_t)b * H_ + tx);
          __syncthreads();
          rv[tx] = sh1a[tx] * p.Wa[tx];
          __syncthreads();
          if (tx < 64) {
            float v = 0.f;
#pragma unroll
            for (int o = 0; o < 8; ++o) v += rv[tx + o * 64];
#pragma unroll
            for (int d = 1; d < 64; d <<= 1) v += __shfl_xor(v, d);
            if (tx == 0) shsS = v;
          }
          __syncthreads();
          if (tx < S_) {
            float sc = tanhf(shsS + wsf[OFF_CS + b * S_ + tx]);
            float e = expf(sc); float sum = e;
#pragma unroll
            for (int d = 1; d < 64; d <<= 1) sum += __shfl_xor(sum, d);
            float w2 = e / sum; wlds[tx] = w2;
            p.out[(size_t)B_ * T_ * V_ + ((size_t)b * T_ + (t + 1)) * S_ + tx] = w2;
          }
          __syncthreads();
          float a0 = 0.f;
          const float* cb = p.ctx + (size_t)b * S_ * C_ + tx;
#pragma unroll 8
          for (int s2 = 0; s2 < S_; ++s2) a0 = fmaf(wlds[s2], cb[(size_t)s2 * C_], a0);
#pragma unroll
          for (int r = 0; r < 8; ++r)
            st_cf(wsf + OFF_ATT + (size_t)r * 16384 + (size_t)b * H_ + tx, a0);
          __syncthreads();
        }
        asm volatile("s_waitcnt vmcnt(0)" ::: "memory");
        __syncthreads();
        if (tx == 0) arrive(cw, 0, 256, 6u * (ut + 2u), ut + 2u);   // attcnt
      }
    }
  }
}

// ---------------- deferred LSE reduction (all t,b) ----------------
__global__ void __launch_bounds__(256) lse_all(float* __restrict__ wsf) {
  const int id = blockIdx.x, tx = threadIdx.x;   // id = t*32+b, 1024 blocks
  __shared__ float rm[256], rs[256];
  rm[tx] = (tx < ND) ? wsf[OFF_LSM + (size_t)id * 256 + tx] : -3.0e38f;
  rs[tx] = (tx < ND) ? wsf[OFF_LSS + (size_t)id * 256 + tx] : 0.f;
  __syncthreads();
  if (tx < 64) {
    float m = rm[tx], s = rs[tx];
#pragma unroll
    for (int o = 64; o < 256; o += 64) lse_merge(m, s, rm[tx + o], rs[tx + o]);
#pragma unroll
    for (int d = 1; d < 64; d <<= 1) {
      float m2 = __shfl_xor(m, d), s2 = __shfl_xor(s, d);
      lse_merge(m, s, m2, s2);
    }
    if (tx == 0) wsf[OFF_LSEA + id] = m + logf(s);
  }
}

// ---------------- final batched logp GEMM (bf16 MFMA) ----------------
__global__ void __launch_bounds__(256) gemm_logp(const unsigned short* __restrict__ h1bf,
                                                 const unsigned short* __restrict__ wobf,
                                                 const float* __restrict__ bo,
                                                 const float* __restrict__ lsea,
                                                 float* __restrict__ out) {
  __shared__ __align__(16) unsigned short As[2][128 * 40];  // rows padded to 80B
  __shared__ __align__(16) unsigned short Bs[2][128 * 40];
  const int tx = threadIdx.x;
  const int v0 = blockIdx.x * 128, m0 = blockIdx.y * 128;
  const int w = tx >> 6, l = tx & 63;
  const int wm = w >> 1, wn = w & 1;
  f32x4 acc[4][4];
#pragma unroll
  for (int i = 0; i < 4; ++i)
#pragma unroll
    for (int j = 0; j < 4; ++j) acc[i][j] = (f32x4){0.f, 0.f, 0.f, 0.f};

#define GSTAGE(ci, kc) {                                                        \
    _Pragma("unroll")                                                           \
    for (int e = 0; e < 2; ++e) {                                               \
      const int seg = tx * 2 + e, row = seg >> 2, s = seg & 3;                  \
      *(uint4*)&As[ci][row * 40 + s * 8] =                                      \
          *(const uint4*)(h1bf + (size_t)(m0 + row) * H_ + (kc) * 32 + s * 8);  \
      *(uint4*)&Bs[ci][row * 40 + s * 8] =                                      \
          *(const uint4*)(wobf + (size_t)(v0 + row) * H_ + (kc) * 32 + s * 8);  \
    } }

  GSTAGE(0, 0);
  __syncthreads();
  for (int kc = 0; kc < 16; ++kc) {
    const int cur = kc & 1;
    if (kc < 15) GSTAGE(cur ^ 1, kc + 1);
    const int lk = (l >> 4) * 8, lr = l & 15;
    bf16x8 af[4], bf[4];
#pragma unroll
    for (int f = 0; f < 4; ++f) {
      af[f] = *(const bf16x8*)&As[cur][(wm * 64 + f * 16 + lr) * 40 + lk];
      bf[f] = *(const bf16x8*)&Bs[cur][(wn * 64 + f * 16 + lr) * 40 + lk];
    }
#pragma unroll
    for (int fm = 0; fm < 4; ++fm)
#pragma unroll
      for (int fn = 0; fn < 4; ++fn)
        acc[fm][fn] = __builtin_amdgcn_mfma_f32_16x16x32_bf16(af[fm], bf[fn], acc[fm][fn], 0, 0, 0);
    __syncthreads();
  }
#undef GSTAGE
  const int lr = l & 15, lq = l >> 4;
#pragma unroll
  for (int fm = 0; fm < 4; ++fm) {
#pragma unroll
    for (int fn = 0; fn < 4; ++fn) {
      const int v = v0 + wn * 64 + fn * 16 + lr;
      const float bov = bo[v];
#pragma unroll
      for (int r = 0; r < 4; ++r) {
        const int M = m0 + wm * 64 + fm * 16 + lq * 4 + r;
        const int tt = M >> 5, b = M & 31;
        out[((size_t)b * T_ + tt) * (size_t)V_ + v] = acc[fm][fn][r] + bov - lsea[tt * B_ + b];
      }
    }
  }
}

// ---------------- host launch ----------------
extern "C" void kernel_launch(void* const* d_in, const int* in_sizes, int n_in,
                              void* d_out, int out_size, void* d_ws, size_t ws_size,
                              hipStream_t stream) {
  (void)in_sizes; (void)n_in; (void)out_size;
  if (ws_size < (size_t)WS_FLOATS * sizeof(float)) return;  // workspace too small

  const float* ctx   = (const float*)d_in[0];
  // d_in[1] = max_len (scalar, == 32, hardcoded)
  const float* embed = (const float*)d_in[2];
  const float* Wa    = (const float*)d_in[3];
  const float* ba    = (const float*)d_in[4];
  const float* Wih0  = (const float*)d_in[5];
  const float* Whh0  = (const float*)d_in[6];
  const float* bih0  = (const float*)d_in[7];
  const float* bhh0  = (const float*)d_in[8];
  const float* Wih1  = (const float*)d_in[9];
  const float* Whh1  = (const float*)d_in[10];
  const float* bih1  = (const float*)d_in[11];
  const float* bhh1  = (const float*)d_in[12];
  const float* Wo    = (const float*)d_in[13];
  const float* bo    = (const float*)d_in[14];
  float* ws  = (float*)d_ws;
  float* out = (float*)d_out;

  zero_k<<<dim3(1024), dim3(256), 0, stream>>>(ws);
  cscore_k<<<dim3(32), dim3(256), 0, stream>>>(ctx, Wa, ba, ws);
  cvt_wobf<<<dim3(16000), dim3(256), 0, stream>>>(Wo, (unsigned short*)(ws + OFF_WOBF));

  Params p;
  p.ctx = ctx; p.embed = embed; p.Wa = Wa;
  p.Wih0 = Wih0; p.Whh0 = Whh0; p.bih0 = bih0; p.bhh0 = bhh0;
  p.Wih1 = Wih1; p.Whh1 = Whh1; p.bih1 = bih1; p.bhh1 = bhh1;
  p.Wo = Wo; p.bo = bo; p.ws = ws; p.out = out;
  mtad_main<<<dim3(NBLK), dim3(NTHR), 0, stream>>>(p);

  lse_all<<<dim3(1024), dim3(256), 0, stream>>>(ws);
  gemm_logp<<<dim3(250, 8), dim3(256), 0, stream>>>(
      (const unsigned short*)(ws + OFF_H1BF), (const unsigned short*)(ws + OFF_WOBF),
      bo, ws + OFF_LSEA, out);
}

// Round 10
// 2597.715 us; speedup vs baseline: 2.0251x; 2.0251x over previous
//
#include <hip/hip_runtime.h>

// ---------------- problem constants ----------------
#define B_ 32
#define S_ 64
#define C_ 512
#define E_ 256
#define H_ 512
#define V_ 32000
#define T_ 32
#define NTHR 512
#define ND 250         // scan blocks (250*128 = 32000); blocks 250..255 = attention
#define START_TOK 1
#define DELTA 0.05f    // candidate window (bf16 logit err sigma ~6e-4)
#define BH (B_ * H_)

// ---------------- workspace layout (float offsets) ----------------
#define OFF_CS   0          // cscore[32][64] = 2048
#define OFF_LSEA 2048       // lse[32 t][32 b] = 1024
#define OFF_GMAX 3072       // u64 gmax[1024] strided *8 (64B apart) = 16384 f
#define OFF_CCNT 19456      // int ccnt[1024] strided *32 = 32768
#define OFF_CLST 52224      // int clist[1024][64] = 65536
#define OFF_LSM  117760     // float [1024][256] = 262144
#define OFF_LSS  379904     // float [1024][256] = 262144
#define OFF_ATT  642048     // attend [32][512] = 16384
#define OFF_H0   658432     // h0[2][32][512] = 32768
#define OFF_H1   691200     // h1[2][32][512] = 32768
#define OFF_H1BF 723968     // history ushort[1024][512] = 262144 f
#define OFF_WOBF 986112     // ushort[32000][512] bf16 Wo = 8192000 f
#define WS_FLOATS 9178112   // ~36.7 MB

typedef unsigned long long ull;
typedef __attribute__((ext_vector_type(8))) short bf16x8;
typedef __attribute__((ext_vector_type(4))) float f32x4;

struct Params {
  const float* ctx; const float* embed; const float* Wa;
  const float* Wih0; const float* Whh0; const float* bih0; const float* bhh0;
  const float* Wih1; const float* Whh1; const float* bih1; const float* bhh1;
  const float* Wo; const float* bo;
  float* ws; float* out;
};

__device__ __forceinline__ float sigf(float x) { return 1.0f / (1.0f + expf(-x)); }

__device__ __forceinline__ unsigned short f2bf(float f) {  // RNE f32->bf16
  unsigned u = __builtin_bit_cast(unsigned, f);
  unsigned r = (u + 0x7FFFu + ((u >> 16) & 1u)) >> 16;
  return (unsigned short)r;
}

__device__ __forceinline__ void lse_merge(float& m, float& s, float m2, float s2) {
  float M = fmaxf(m, m2);
  s = s * expf(m - M) + s2 * expf(m2 - M);
  m = M;
}

// argmax packing: monotone f32->u32, tie-break smallest idx via ~idx
__device__ __forceinline__ ull packvi(float v, int idx) {
  unsigned u = __builtin_bit_cast(unsigned, v);
  unsigned m = (u & 0x80000000u) ? ~u : (u | 0x80000000u);
  return ((ull)m << 32) | (ull)(~(unsigned)idx);
}
__device__ __forceinline__ float unpackv(ull g) {
  unsigned m = (unsigned)(g >> 32);
  unsigned raw = (m & 0x80000000u) ? (m & 0x7fffffffu) : ~m;
  return __builtin_bit_cast(float, raw);
}

// ---------------- prologue kernels ----------------
__global__ void __launch_bounds__(256) zero_k(float* wsf) {
  const unsigned i = blockIdx.x * 256u + threadIdx.x;
  if (i < 49152u) wsf[OFF_GMAX + i] = 0.0f;             // gmax + ccnt
  if (i < 65536u) wsf[OFF_H0 + i] = 0.0f;               // h0[2] + h1[2]
}

__global__ void __launch_bounds__(256) cscore_k(const float* __restrict__ ctx,
                                                const float* __restrict__ Wa,
                                                const float* __restrict__ ba,
                                                float* __restrict__ wsf) {
  const int b = blockIdx.x;
  const int s = threadIdx.x >> 2, q = threadIdx.x & 3;
  const float* cp = ctx + ((size_t)b * S_ + s) * C_ + q * 128;
  const float* wp = Wa + H_ + q * 128;     // context half of Wa
  float acc = 0.f;
#pragma unroll 8
  for (int k = 0; k < 128; ++k) acc = fmaf(cp[k], wp[k], acc);
  acc += __shfl_xor(acc, 1);
  acc += __shfl_xor(acc, 2);
  if (q == 0) wsf[OFF_CS + b * S_ + s] = acc + ba[0];
}

__global__ void __launch_bounds__(256) cvt_wobf(const float* __restrict__ wo,
                                                unsigned short* __restrict__ dst) {
  const size_t i = ((size_t)blockIdx.x * 256u + threadIdx.x) * 4;
  float4 v = *(const float4*)(wo + i);
  ushort4 o;
  o.x = f2bf(v.x); o.y = f2bf(v.y); o.z = f2bf(v.z); o.w = f2bf(v.w);
  *(ushort4*)(dst + i) = o;
}

// attention for t=0 (h1 = 0 -> hscore = 0)
__global__ void __launch_bounds__(NTHR) attn0_k(const float* __restrict__ ctx,
                                                float* __restrict__ wsf,
                                                float* __restrict__ out) {
  const int b = blockIdx.x, tx = threadIdx.x;
  __shared__ float wlds[S_];
  if (tx < S_) {
    float sc = tanhf(wsf[OFF_CS + b * S_ + tx]);
    float e = expf(sc); float sum = e;
#pragma unroll
    for (int d = 1; d < 64; d <<= 1) sum += __shfl_xor(sum, d);
    float w = e / sum; wlds[tx] = w;
    out[(size_t)B_ * T_ * V_ + ((size_t)b * T_ + 0) * S_ + tx] = w;
  }
  __syncthreads();
  float a0 = 0.f;
  const float* cb = ctx + (size_t)b * S_ * C_ + tx;
#pragma unroll 8
  for (int s2 = 0; s2 < S_; ++s2) a0 = fmaf(wlds[s2], cb[(size_t)s2 * C_], a0);
  wsf[OFF_ATT + (size_t)b * H_ + tx] = a0;
}

// ---------------- per-step kernel 1: resolve + embed + GRU layer 0 ----------------
__global__ void __launch_bounds__(NTHR) k_gru0(Params p, int t) {
  float* wsf = p.ws;
  const int bk = blockIdx.x, tx = threadIdx.x;
  const int ug = bk & 31, bg = bk >> 5, b4 = bg * 4;
  const int par = t & 1;
  __shared__ __align__(16) float sacts[4 * 768];
  __shared__ __align__(16) float sh0l[4 * 512];
  __shared__ __align__(16) float sh1r[4 * 512];
  __shared__ int   stok4[4];
  __shared__ float scrV[8];
  __shared__ int   scrI[8];

  // stage attend + h0_prev + h1_prev (plain cached float4 loads)
  {
    const int bb = tx >> 7, cc = (tx & 127) * 4;
    float4 va = *(const float4*)(wsf + OFF_ATT + (size_t)(b4 + bb) * H_ + cc);
    float4 vh = *(const float4*)(wsf + OFF_H0 + (size_t)par * BH + (size_t)(b4 + bb) * H_ + cc);
    float4 vr = *(const float4*)(wsf + OFF_H1 + (size_t)par * BH + (size_t)(b4 + bb) * H_ + cc);
    *(float4*)&sacts[bb * 768 + 256 + cc] = va;
    *(float4*)&sh0l[bb * 512 + cc] = vh;
    *(float4*)&sh1r[bb * 512 + cc] = vr;
  }
  __syncthreads();
  // resolve tokens for this block's 4 batches (redundant per block)
  if (t > 0) {
    const int w = tx >> 6, lane = tx & 63;
    const int lb = w >> 1, ws2 = w & 1, b = b4 + lb;
    const int cb_ = (t - 1) * 32 + b;
    int nc = ((const int*)wsf)[OFF_CCNT + (size_t)cb_ * 32];
    if (nc > 64) nc = 64;
    float bV = -3.0e38f; int bI = 0x7fffffff;
    for (int c = ws2; c < nc; c += 2) {
      const int idx = ((const int*)wsf)[OFF_CLST + (size_t)cb_ * 64 + c];
      const float* wr = p.Wo + (size_t)idx * H_ + lane * 8;
      const float* hr = sh1r + lb * 512 + lane * 8;
      float a = 0.f;
#pragma unroll
      for (int e = 0; e < 8; ++e) a = fmaf(hr[e], wr[e], a);
#pragma unroll
      for (int d = 1; d < 64; d <<= 1) a += __shfl_xor(a, d);
      a += p.bo[idx];
      if (a > bV || (a == bV && idx < bI)) { bV = a; bI = idx; }
    }
    if (lane == 0) { scrV[w] = bV; scrI[w] = bI; }
    __syncthreads();
    if (tx < 4) {
      float v0 = scrV[tx * 2], v1 = scrV[tx * 2 + 1];
      int i0 = scrI[tx * 2], i1 = scrI[tx * 2 + 1];
      stok4[tx] = (v1 > v0 || (v1 == v0 && i1 < i0)) ? i1 : i0;
    }
  } else {
    if (tx < 4) stok4[tx] = START_TOK;
  }
  __syncthreads();
  // stage embed
#pragma unroll
  for (int k = 0; k < 2; ++k) {
    const int idx = k * NTHR + tx;
    const int bb = idx >> 8, e = idx & 255;
    sacts[bb * 768 + e] = p.embed[(size_t)stok4[bb] * E_ + e];
  }
  __syncthreads();
  // GRU0 gates
  const int u = tx >> 5, l = tx & 31;
  const int j = ug * 16 + u;
  float red[16];
#pragma unroll
  for (int q = 0; q < 16; ++q) red[q] = 0.f;
#pragma unroll
  for (int g = 0; g < 3; ++g) {
    const float4* wx = (const float4*)(p.Wih0 + (size_t)(g * H_ + j) * 768);
    float* dx = (g < 2) ? &red[g * 4] : &red[8];
#pragma unroll
    for (int c = 0; c < 6; ++c) {
      float4 w = wx[l + 32 * c];
#pragma unroll
      for (int b2 = 0; b2 < 4; ++b2) {
        const float* a = &sacts[b2 * 768 + 4 * l + 128 * c];
        dx[b2] = fmaf(w.x, a[0], dx[b2]); dx[b2] = fmaf(w.y, a[1], dx[b2]);
        dx[b2] = fmaf(w.z, a[2], dx[b2]); dx[b2] = fmaf(w.w, a[3], dx[b2]);
      }
    }
    const float4* wh = (const float4*)(p.Whh0 + (size_t)(g * H_ + j) * H_);
    float* dh = (g < 2) ? &red[g * 4] : &red[12];
#pragma unroll
    for (int c = 0; c < 4; ++c) {
      float4 w = wh[l + 32 * c];
#pragma unroll
      for (int b2 = 0; b2 < 4; ++b2) {
        const float* a = &sh0l[b2 * 512 + 4 * l + 128 * c];
        dh[b2] = fmaf(w.x, a[0], dh[b2]); dh[b2] = fmaf(w.y, a[1], dh[b2]);
        dh[b2] = fmaf(w.z, a[2], dh[b2]); dh[b2] = fmaf(w.w, a[3], dh[b2]);
      }
    }
  }
#pragma unroll
  for (int d = 1; d < 32; d <<= 1)
#pragma unroll
    for (int q = 0; q < 16; ++q) red[q] += __shfl_xor(red[q], d);
  if (l < 4) {
    const float rr = sigf(red[l] + p.bih0[j] + p.bhh0[j]);
    const float zz = sigf(red[4 + l] + p.bih0[H_ + j] + p.bhh0[H_ + j]);
    const float nn = tanhf(red[8 + l] + p.bih0[2 * H_ + j] +
                           rr * (red[12 + l] + p.bhh0[2 * H_ + j]));
    const float hp = sh0l[l * 512 + j];
    wsf[OFF_H0 + (size_t)(1 - par) * BH + (size_t)(b4 + l) * H_ + j] =
        (1.f - zz) * nn + zz * hp;
  }
}

// ---------------- per-step kernel 2: GRU layer 1 ----------------
__global__ void __launch_bounds__(NTHR) k_gru1(Params p, int t) {
  float* wsf = p.ws;
  unsigned short* h1bf = (unsigned short*)(wsf + OFF_H1BF);
  const int bk = blockIdx.x, tx = threadIdx.x;
  const int ug = bk & 31, bg = bk >> 5, b4 = bg * 4;
  const int par = t & 1;
  __shared__ __align__(16) float sx[4 * 512];
  __shared__ __align__(16) float sh[4 * 512];
  __shared__ float hout[64];
  {
    const int bb = tx >> 7, cc = (tx & 127) * 4;
    float4 vx = *(const float4*)(wsf + OFF_H0 + (size_t)(1 - par) * BH + (size_t)(b4 + bb) * H_ + cc);
    float4 vh = *(const float4*)(wsf + OFF_H1 + (size_t)par * BH + (size_t)(b4 + bb) * H_ + cc);
    *(float4*)&sx[bb * 512 + cc] = vx;
    *(float4*)&sh[bb * 512 + cc] = vh;
  }
  __syncthreads();
  const int u = tx >> 5, l = tx & 31;
  const int j = ug * 16 + u;
  float red[16];
#pragma unroll
  for (int q = 0; q < 16; ++q) red[q] = 0.f;
#pragma unroll
  for (int g = 0; g < 3; ++g) {
    const float4* wx = (const float4*)(p.Wih1 + (size_t)(g * H_ + j) * H_);
    float* dx = (g < 2) ? &red[g * 4] : &red[8];
#pragma unroll
    for (int c = 0; c < 4; ++c) {
      float4 w = wx[l + 32 * c];
#pragma unroll
      for (int b2 = 0; b2 < 4; ++b2) {
        const float* a = &sx[b2 * 512 + 4 * l + 128 * c];
        dx[b2] = fmaf(w.x, a[0], dx[b2]); dx[b2] = fmaf(w.y, a[1], dx[b2]);
        dx[b2] = fmaf(w.z, a[2], dx[b2]); dx[b2] = fmaf(w.w, a[3], dx[b2]);
      }
    }
    const float4* wh = (const float4*)(p.Whh1 + (size_t)(g * H_ + j) * H_);
    float* dh = (g < 2) ? &red[g * 4] : &red[12];
#pragma unroll
    for (int c = 0; c < 4; ++c) {
      float4 w = wh[l + 32 * c];
#pragma unroll
      for (int b2 = 0; b2 < 4; ++b2) {
        const float* a = &sh[b2 * 512 + 4 * l + 128 * c];
        dh[b2] = fmaf(w.x, a[0], dh[b2]); dh[b2] = fmaf(w.y, a[1], dh[b2]);
        dh[b2] = fmaf(w.z, a[2], dh[b2]); dh[b2] = fmaf(w.w, a[3], dh[b2]);
      }
    }
  }
#pragma unroll
  for (int d = 1; d < 32; d <<= 1)
#pragma unroll
    for (int q = 0; q < 16; ++q) red[q] += __shfl_xor(red[q], d);
  if (l < 4) {
    const float rr = sigf(red[l] + p.bih1[j] + p.bhh1[j]);
    const float zz = sigf(red[4 + l] + p.bih1[H_ + j] + p.bhh1[H_ + j]);
    const float nn = tanhf(red[8 + l] + p.bih1[2 * H_ + j] +
                           rr * (red[12 + l] + p.bhh1[2 * H_ + j]));
    const float hp = sh[l * 512 + j];
    const float hnew = (1.f - zz) * nn + zz * hp;
    wsf[OFF_H1 + (size_t)(1 - par) * BH + (size_t)(b4 + l) * H_ + j] = hnew;
    hout[u * 4 + l] = hnew;
  }
  __syncthreads();
  if (tx < 32) {   // bf16 pack (2 units / dword) -> h1bf[t]
    const int b2 = tx & 3, pp = tx >> 2;
    const float h0v = hout[(pp * 2) * 4 + b2];
    const float h1v = hout[(pp * 2 + 1) * 4 + b2];
    const unsigned pk = (unsigned)f2bf(h0v) | ((unsigned)f2bf(h1v) << 16);
    *(int*)(h1bf + ((size_t)t * B_ + b4 + b2) * H_ + ug * 16 + pp * 2) = (int)pk;
  }
}

// attention batch split over 6 blocks
__device__ __constant__ int AST[7] = {0, 6, 12, 17, 22, 27, 32};

// ---------------- per-step kernel 3: vocab scan + attention(t+1) ----------------
__global__ void __launch_bounds__(NTHR) k_scan(Params p, int t) {
  float* wsf = p.ws;
  const unsigned short* h1bf = (const unsigned short*)(wsf + OFF_H1BF);
  const unsigned short* wobf = (const unsigned short*)(wsf + OFF_WOBF);
  const int bk = blockIdx.x, tx = threadIdx.x;
  const int par = t & 1;
  __shared__ float scrF[8][16][4];
  __shared__ int   scrI2[8][16][2];
  __shared__ float wlds[S_];
  __shared__ float shsS;
  __shared__ float rv[NTHR];

  if (bk < ND) {
    const int v0 = bk * 128;
    const int w = tx >> 6, l = tx & 63, lr = l & 15, lq = l >> 4;
    const int vr = w * 16 + lr;
    const unsigned short* brow = wobf + (size_t)(v0 + vr) * H_ + lq * 8;
    for (int bt = 0; bt < 2; ++bt) {
      const unsigned short* arow = h1bf + ((size_t)t * B_ + bt * 16 + lr) * H_ + lq * 8;
      f32x4 acc = {0.f, 0.f, 0.f, 0.f};
#pragma unroll 4
      for (int kc = 0; kc < 16; ++kc) {
        bf16x8 a = *(const bf16x8*)(arow + kc * 32);
        bf16x8 bv = *(const bf16x8*)(brow + kc * 32);
        acc = __builtin_amdgcn_mfma_f32_16x16x32_bf16(a, bv, acc, 0, 0, 0);
      }
      const float bov = p.bo[v0 + vr];
#pragma unroll
      for (int r = 0; r < 4; ++r) {
        float v1 = acc[r] + bov, v2 = -3.0e38f;
        int i1 = v0 + vr, i2 = 0x7fffffff;
        float m = v1, s = 1.0f;
#pragma unroll
        for (int d = 1; d < 16; d <<= 1) {
          float w1 = __shfl_xor(v1, d); int j1 = __shfl_xor(i1, d);
          float w2 = __shfl_xor(v2, d); int j2 = __shfl_xor(i2, d);
          float m2 = __shfl_xor(m, d);  float s2 = __shfl_xor(s, d);
          if (w1 > v1 || (w1 == v1 && j1 < i1)) { v2 = v1; i2 = i1; v1 = w1; i1 = j1; }
          else if (w1 > v2 || (w1 == v2 && j1 < i2)) { v2 = w1; i2 = j1; }
          if (w2 > v2 || (w2 == v2 && j2 < i2)) {
            if (w2 > v1 || (w2 == v1 && j2 < i1)) { v2 = v1; i2 = i1; v1 = w2; i1 = j2; }
            else { v2 = w2; i2 = j2; }
          }
          lse_merge(m, s, m2, s2);
        }
        if (lr == 0) {
          const int bb = lq * 4 + r;
          scrF[w][bb][0] = v1; scrF[w][bb][1] = v2;
          scrF[w][bb][2] = m;  scrF[w][bb][3] = s;
          scrI2[w][bb][0] = i1; scrI2[w][bb][1] = i2;
        }
      }
      __syncthreads();
      if (tx < 16) {   // combine 8 waves; publish partials + argmax candidates
        float v1 = scrF[0][tx][0], v2 = scrF[0][tx][1];
        float m = scrF[0][tx][2], s = scrF[0][tx][3];
        int i1 = scrI2[0][tx][0], i2 = scrI2[0][tx][1];
#pragma unroll
        for (int ww = 1; ww < 8; ++ww) {
          float w1 = scrF[ww][tx][0]; int j1 = scrI2[ww][tx][0];
          float w2 = scrF[ww][tx][1]; int j2 = scrI2[ww][tx][1];
          if (w1 > v1 || (w1 == v1 && j1 < i1)) { v2 = v1; i2 = i1; v1 = w1; i1 = j1; }
          else if (w1 > v2 || (w1 == v2 && j1 < i2)) { v2 = w1; i2 = j1; }
          if (w2 > v2 || (w2 == v2 && j2 < i2)) {
            if (w2 > v1 || (w2 == v1 && j2 < i1)) { v2 = v1; i2 = i1; v1 = w2; i1 = j2; }
            else { v2 = w2; i2 = j2; }
          }
          lse_merge(m, s, scrF[ww][tx][2], scrF[ww][tx][3]);
        }
        const int b = bt * 16 + tx;
        const size_t cb = (size_t)(t * 32 + b);
        wsf[OFF_LSM + cb * 256 + bk] = m;
        wsf[OFF_LSS + cb * 256 + bk] = s;
        ull pk1 = packvi(v1, i1);
        ull* gm = (ull*)(wsf + OFF_GMAX) + cb * 8;
        ull old = __hip_atomic_fetch_max(gm, pk1, __ATOMIC_RELAXED,
                                         __HIP_MEMORY_SCOPE_AGENT);
        ull cur = old > pk1 ? old : pk1;
        float curv = unpackv(cur);
        int* ccp = (int*)wsf + OFF_CCNT + cb * 32;
        int* clp = (int*)wsf + OFF_CLST + cb * 64;
        if (v1 >= curv - DELTA) {
          int k = __hip_atomic_fetch_add(ccp, 1, __ATOMIC_RELAXED,
                                         __HIP_MEMORY_SCOPE_AGENT);
          if (k < 64) clp[k] = i1;
        }
        if (i2 != 0x7fffffff && v2 >= curv - DELTA) {
          int k = __hip_atomic_fetch_add(ccp, 1, __ATOMIC_RELAXED,
                                         __HIP_MEMORY_SCOPE_AGENT);
          if (k < 64) clp[k] = i2;
        }
      }
      __syncthreads();
    }
  } else if (t < T_ - 1) {       // attention for step t+1 using h1(t)
    const int q = bk - ND;
    for (int b = AST[q]; b < AST[q + 1]; ++b) {
      const float h1v = wsf[OFF_H1 + (size_t)(1 - par) * BH + (size_t)b * H_ + tx];
      rv[tx] = h1v * p.Wa[tx];
      __syncthreads();
      if (tx < 64) {
        float v = 0.f;
#pragma unroll
        for (int o = 0; o < 8; ++o) v += rv[tx + o * 64];
#pragma unroll
        for (int d = 1; d < 64; d <<= 1) v += __shfl_xor(v, d);
        if (tx == 0) shsS = v;
      }
      __syncthreads();
      if (tx < S_) {
        float sc = tanhf(shsS + wsf[OFF_CS + b * S_ + tx]);
        float e = expf(sc); float sum = e;
#pragma unroll
        for (int d = 1; d < 64; d <<= 1) sum += __shfl_xor(sum, d);
        float w2 = e / sum; wlds[tx] = w2;
        p.out[(size_t)B_ * T_ * V_ + ((size_t)b * T_ + (t + 1)) * S_ + tx] = w2;
      }
      __syncthreads();
      float a0 = 0.f;
      const float* cb = p.ctx + (size_t)b * S_ * C_ + tx;
#pragma unroll 8
      for (int s2 = 0; s2 < S_; ++s2) a0 = fmaf(wlds[s2], cb[(size_t)s2 * C_], a0);
      wsf[OFF_ATT + (size_t)b * H_ + tx] = a0;
      __syncthreads();
    }
  }
}

// ---------------- deferred LSE reduction (all t,b) ----------------
__global__ void __launch_bounds__(256) lse_all(float* __restrict__ wsf) {
  const int id = blockIdx.x, tx = threadIdx.x;   // id = t*32+b
  __shared__ float rm[256], rs[256];
  rm[tx] = (tx < ND) ? wsf[OFF_LSM + (size_t)id * 256 + tx] : -3.0e38f;
  rs[tx] = (tx < ND) ? wsf[OFF_LSS + (size_t)id * 256 + tx] : 0.f;
  __syncthreads();
  if (tx < 64) {
    float m = rm[tx], s = rs[tx];
#pragma unroll
    for (int o = 64; o < 256; o += 64) lse_merge(m, s, rm[tx + o], rs[tx + o]);
#pragma unroll
    for (int d = 1; d < 64; d <<= 1) {
      float m2 = __shfl_xor(m, d), s2 = __shfl_xor(s, d);
      lse_merge(m, s, m2, s2);
    }
    if (tx == 0) wsf[OFF_LSEA + id] = m + logf(s);
  }
}

// ---------------- final batched logp GEMM (bf16 MFMA) ----------------
__global__ void __launch_bounds__(256) gemm_logp(const unsigned short* __restrict__ h1bf,
                                                 const unsigned short* __restrict__ wobf,
                                                 const float* __restrict__ bo,
                                                 const float* __restrict__ lsea,
                                                 float* __restrict__ out) {
  __shared__ __align__(16) unsigned short As[2][128 * 40];  // rows padded to 80B
  __shared__ __align__(16) unsigned short Bs[2][128 * 40];
  const int tx = threadIdx.x;
  const int v0 = blockIdx.x * 128, m0 = blockIdx.y * 128;
  const int w = tx >> 6, l = tx & 63;
  const int wm = w >> 1, wn = w & 1;
  f32x4 acc[4][4];
#pragma unroll
  for (int i = 0; i < 4; ++i)
#pragma unroll
    for (int j = 0; j < 4; ++j) acc[i][j] = (f32x4){0.f, 0.f, 0.f, 0.f};

#define GSTAGE(ci, kc) {                                                        \
    _Pragma("unroll")                                                           \
    for (int e = 0; e < 2; ++e) {                                               \
      const int seg = tx * 2 + e, row = seg >> 2, s = seg & 3;                  \
      *(uint4*)&As[ci][row * 40 + s * 8] =                                      \
          *(const uint4*)(h1bf + (size_t)(m0 + row) * H_ + (kc) * 32 + s * 8);  \
      *(uint4*)&Bs[ci][row * 40 + s * 8] =                                      \
          *(const uint4*)(wobf + (size_t)(v0 + row) * H_ + (kc) * 32 + s * 8);  \
    } }

  GSTAGE(0, 0);
  __syncthreads();
  for (int kc = 0; kc < 16; ++kc) {
    const int cur = kc & 1;
    if (kc < 15) GSTAGE(cur ^ 1, kc + 1);
    const int lk = (l >> 4) * 8, lr = l & 15;
    bf16x8 af[4], bf[4];
#pragma unroll
    for (int f = 0; f < 4; ++f) {
      af[f] = *(const bf16x8*)&As[cur][(wm * 64 + f * 16 + lr) * 40 + lk];
      bf[f] = *(const bf16x8*)&Bs[cur][(wn * 64 + f * 16 + lr) * 40 + lk];
    }
#pragma unroll
    for (int fm = 0; fm < 4; ++fm)
#pragma unroll
      for (int fn = 0; fn < 4; ++fn)
        acc[fm][fn] = __builtin_amdgcn_mfma_f32_16x16x32_bf16(af[fm], bf[fn], acc[fm][fn], 0, 0, 0);
    __syncthreads();
  }
#undef GSTAGE
  const int lr = l & 15, lq = l >> 4;
#pragma unroll
  for (int fm = 0; fm < 4; ++fm) {
#pragma unroll
    for (int fn = 0; fn < 4; ++fn) {
      const int v = v0 + wn * 64 + fn * 16 + lr;
      const float bov = bo[v];
#pragma unroll
      for (int r = 0; r < 4; ++r) {
        const int M = m0 + wm * 64 + fm * 16 + lq * 4 + r;
        const int tt = M >> 5, b = M & 31;
        out[((size_t)b * T_ + tt) * (size_t)V_ + v] = acc[fm][fn][r] + bov - lsea[tt * B_ + b];
      }
    }
  }
}

// ---------------- host launch ----------------
extern "C" void kernel_launch(void* const* d_in, const int* in_sizes, int n_in,
                              void* d_out, int out_size, void* d_ws, size_t ws_size,
                              hipStream_t stream) {
  (void)in_sizes; (void)n_in; (void)out_size;
  if (ws_size < (size_t)WS_FLOATS * sizeof(float)) return;  // workspace too small

  const float* ctx   = (const float*)d_in[0];
  // d_in[1] = max_len (scalar, == 32, hardcoded)
  const float* embed = (const float*)d_in[2];
  const float* Wa    = (const float*)d_in[3];
  const float* ba    = (const float*)d_in[4];
  const float* Wih0  = (const float*)d_in[5];
  const float* Whh0  = (const float*)d_in[6];
  const float* bih0  = (const float*)d_in[7];
  const float* bhh0  = (const float*)d_in[8];
  const float* Wih1  = (const float*)d_in[9];
  const float* Whh1  = (const float*)d_in[10];
  const float* bih1  = (const float*)d_in[11];
  const float* bhh1  = (const float*)d_in[12];
  const float* Wo    = (const float*)d_in[13];
  const float* bo    = (const float*)d_in[14];
  float* ws  = (float*)d_ws;
  float* out = (float*)d_out;

  zero_k<<<dim3(256), dim3(256), 0, stream>>>(ws);
  cscore_k<<<dim3(32), dim3(256), 0, stream>>>(ctx, Wa, ba, ws);
  cvt_wobf<<<dim3(16000), dim3(256), 0, stream>>>(Wo, (unsigned short*)(ws + OFF_WOBF));
  attn0_k<<<dim3(32), dim3(NTHR), 0, stream>>>(ctx, ws, out);

  Params p;
  p.ctx = ctx; p.embed = embed; p.Wa = Wa;
  p.Wih0 = Wih0; p.Whh0 = Whh0; p.bih0 = bih0; p.bhh0 = bhh0;
  p.Wih1 = Wih1; p.Whh1 = Whh1; p.bih1 = bih1; p.bhh1 = bhh1;
  p.Wo = Wo; p.bo = bo; p.ws = ws; p.out = out;

  for (int t = 0; t < T_; ++t) {
    k_gru0<<<dim3(256), dim3(NTHR), 0, stream>>>(p, t);
    k_gru1<<<dim3(256), dim3(NTHR), 0, stream>>>(p, t);
    k_scan<<<dim3(256), dim3(NTHR), 0, stream>>>(p, t);
  }

  lse_all<<<dim3(1024), dim3(256), 0, stream>>>(ws);
  gemm_logp<<<dim3(250, 8), dim3(256), 0, stream>>>(
      (const unsigned short*)(ws + OFF_H1BF), (const unsigned short*)(ws + OFF_WOBF),
      bo, ws + OFF_LSEA, out);
}

// Round 11
// 2592.993 us; speedup vs baseline: 2.0288x; 1.0018x over previous
//
#include <hip/hip_runtime.h>

// ---------------- problem constants ----------------
#define B_ 32
#define S_ 64
#define C_ 512
#define E_ 256
#define H_ 512
#define V_ 32000
#define T_ 32
#define NTHR 512
#define ND 250         // scan blocks (250*128 = 32000); blocks 250..255 = attention
#define START_TOK 1
#define DELTA 0.05f    // candidate window (bf16 logit err sigma ~6e-4)
#define BH (B_ * H_)

// ---------------- workspace layout (float offsets) ----------------
#define OFF_CS   0          // cscore[32][64] = 2048
#define OFF_LSEA 2048       // lse[32 t][32 b] = 1024
#define OFF_GMAX 3072       // u64 gmax[1024] strided *8 (64B apart) = 16384 f
#define OFF_CCNT 19456      // int ccnt[1024] strided *32 = 32768
#define OFF_CLST 52224      // int clist[1024][64] = 65536
#define OFF_LSM  117760     // float [1024][256] = 262144
#define OFF_LSS  379904     // float [1024][256] = 262144
#define OFF_ATT  642048     // attend [32][512] = 16384
#define OFF_H0   658432     // h0[2][32][512] = 32768
#define OFF_H1   691200     // h1[2][32][512] = 32768
#define OFF_H1BF 723968     // history ushort[1024][512] = 262144 f
#define OFF_WOBF 986112     // ushort[32000][512] bf16 Wo = 8192000 f
#define OFF_SYNC 9178112    // int cnt[8 bg][128] (slot t in [0,32)) = 1024
#define WS_FLOATS 9179136   // ~36.7 MB

typedef unsigned long long ull;
typedef __attribute__((ext_vector_type(8))) short bf16x8;
typedef __attribute__((ext_vector_type(4))) float f32x4;

struct Params {
  const float* ctx; const float* embed; const float* Wa;
  const float* Wih0; const float* Whh0; const float* bih0; const float* bhh0;
  const float* Wih1; const float* Whh1; const float* bih1; const float* bhh1;
  const float* Wo; const float* bo;
  float* ws; float* out;
};

__device__ __forceinline__ float sigf(float x) { return 1.0f / (1.0f + expf(-x)); }

__device__ __forceinline__ unsigned short f2bf(float f) {  // RNE f32->bf16
  unsigned u = __builtin_bit_cast(unsigned, f);
  unsigned r = (u + 0x7FFFu + ((u >> 16) & 1u)) >> 16;
  return (unsigned short)r;
}

__device__ __forceinline__ void lse_merge(float& m, float& s, float m2, float s2) {
  float M = fmaxf(m, m2);
  s = s * expf(m - M) + s2 * expf(m2 - M);
  m = M;
}

// ---- coherent (L2-bypass) access for the h0 intra-kernel handoff ----
__device__ __forceinline__ void st_cf(float* p, float v) {
  __hip_atomic_store(p, v, __ATOMIC_RELAXED, __HIP_MEMORY_SCOPE_AGENT);
}
__device__ __forceinline__ unsigned ld_cu(const unsigned* p) {
  return __hip_atomic_load(p, __ATOMIC_RELAXED, __HIP_MEMORY_SCOPE_AGENT);
}

// argmax packing: monotone f32->u32, tie-break smallest idx via ~idx
__device__ __forceinline__ ull packvi(float v, int idx) {
  unsigned u = __builtin_bit_cast(unsigned, v);
  unsigned m = (u & 0x80000000u) ? ~u : (u | 0x80000000u);
  return ((ull)m << 32) | (ull)(~(unsigned)idx);
}
__device__ __forceinline__ float unpackv(ull g) {
  unsigned m = (unsigned)(g >> 32);
  unsigned raw = (m & 0x80000000u) ? (m & 0x7fffffffu) : ~m;
  return __builtin_bit_cast(float, raw);
}

// ---------------- prologue kernels ----------------
__global__ void __launch_bounds__(256) zero_k(float* wsf) {
  const unsigned i = blockIdx.x * 256u + threadIdx.x;
  if (i < 49152u) wsf[OFF_GMAX + i] = 0.0f;             // gmax + ccnt
  if (i < 65536u) wsf[OFF_H0 + i] = 0.0f;               // h0[2] + h1[2]
  if (i < 1024u) ((unsigned*)wsf)[OFF_SYNC + i] = 0u;   // bg-sync counters
}

__global__ void __launch_bounds__(256) cscore_k(const float* __restrict__ ctx,
                                                const float* __restrict__ Wa,
                                                const float* __restrict__ ba,
                                                float* __restrict__ wsf) {
  const int b = blockIdx.x;
  const int s = threadIdx.x >> 2, q = threadIdx.x & 3;
  const float* cp = ctx + ((size_t)b * S_ + s) * C_ + q * 128;
  const float* wp = Wa + H_ + q * 128;     // context half of Wa
  float acc = 0.f;
#pragma unroll 8
  for (int k = 0; k < 128; ++k) acc = fmaf(cp[k], wp[k], acc);
  acc += __shfl_xor(acc, 1);
  acc += __shfl_xor(acc, 2);
  if (q == 0) wsf[OFF_CS + b * S_ + s] = acc + ba[0];
}

__global__ void __launch_bounds__(256) cvt_wobf(const float* __restrict__ wo,
                                                unsigned short* __restrict__ dst) {
  const size_t i = ((size_t)blockIdx.x * 256u + threadIdx.x) * 4;
  float4 v = *(const float4*)(wo + i);
  ushort4 o;
  o.x = f2bf(v.x); o.y = f2bf(v.y); o.z = f2bf(v.z); o.w = f2bf(v.w);
  *(ushort4*)(dst + i) = o;
}

// attention for t=0 (h1 = 0 -> hscore = 0)
__global__ void __launch_bounds__(NTHR) attn0_k(const float* __restrict__ ctx,
                                                float* __restrict__ wsf,
                                                float* __restrict__ out) {
  const int b = blockIdx.x, tx = threadIdx.x;
  __shared__ float wlds[S_];
  if (tx < S_) {
    float sc = tanhf(wsf[OFF_CS + b * S_ + tx]);
    float e = expf(sc); float sum = e;
#pragma unroll
    for (int d = 1; d < 64; d <<= 1) sum += __shfl_xor(sum, d);
    float w = e / sum; wlds[tx] = w;
    out[(size_t)B_ * T_ * V_ + ((size_t)b * T_ + 0) * S_ + tx] = w;
  }
  __syncthreads();
  float a0 = 0.f;
  const float* cb = ctx + (size_t)b * S_ * C_ + tx;
#pragma unroll 8
  for (int s2 = 0; s2 < S_; ++s2) a0 = fmaf(wlds[s2], cb[(size_t)s2 * C_], a0);
  wsf[OFF_ATT + (size_t)b * H_ + tx] = a0;
}

// ======== fused per-step kernel 1: resolve + embed + GRU0 | bg-sync | GRU1 ========
__global__ void __launch_bounds__(NTHR) k_gru01(Params p, int t) {
  float* wsf = p.ws;
  unsigned short* h1bf = (unsigned short*)(wsf + OFF_H1BF);
  const int bk = blockIdx.x, tx = threadIdx.x;
  const int ug = bk & 31, bg = bk >> 5, b4 = bg * 4;
  const int par = t & 1;
  __shared__ __align__(16) float sacts[4 * 768];
  __shared__ __align__(16) float sh0l[4 * 512];
  __shared__ __align__(16) float sh1r[4 * 512];   // h1_prev (resolve + GRU1)
  __shared__ __align__(16) float sx[4 * 512];     // h0_new (phase 2)
  __shared__ int   stok4[4];
  __shared__ float scrV[8];
  __shared__ int   scrI[8];
  __shared__ float hout[64];

  // ---------------- phase 1: stage (plain cached loads) ----------------
  {
    const int bb = tx >> 7, cc = (tx & 127) * 4;
    float4 va = *(const float4*)(wsf + OFF_ATT + (size_t)(b4 + bb) * H_ + cc);
    float4 vh = *(const float4*)(wsf + OFF_H0 + (size_t)par * BH + (size_t)(b4 + bb) * H_ + cc);
    float4 vr = *(const float4*)(wsf + OFF_H1 + (size_t)par * BH + (size_t)(b4 + bb) * H_ + cc);
    *(float4*)&sacts[bb * 768 + 256 + cc] = va;
    *(float4*)&sh0l[bb * 512 + cc] = vh;
    *(float4*)&sh1r[bb * 512 + cc] = vr;
  }
  __syncthreads();
  // resolve tokens for this block's 4 batches (redundant per block)
  if (t > 0) {
    const int w = tx >> 6, lane = tx & 63;
    const int lb = w >> 1, ws2 = w & 1, b = b4 + lb;
    const int cb_ = (t - 1) * 32 + b;
    int nc = ((const int*)wsf)[OFF_CCNT + (size_t)cb_ * 32];
    if (nc > 64) nc = 64;
    float bV = -3.0e38f; int bI = 0x7fffffff;
    for (int c = ws2; c < nc; c += 2) {
      const int idx = ((const int*)wsf)[OFF_CLST + (size_t)cb_ * 64 + c];
      const float* wr = p.Wo + (size_t)idx * H_ + lane * 8;
      const float* hr = sh1r + lb * 512 + lane * 8;
      float a = 0.f;
#pragma unroll
      for (int e = 0; e < 8; ++e) a = fmaf(hr[e], wr[e], a);
#pragma unroll
      for (int d = 1; d < 64; d <<= 1) a += __shfl_xor(a, d);
      a += p.bo[idx];
      if (a > bV || (a == bV && idx < bI)) { bV = a; bI = idx; }
    }
    if (lane == 0) { scrV[w] = bV; scrI[w] = bI; }
    __syncthreads();
    if (tx < 4) {
      float v0 = scrV[tx * 2], v1 = scrV[tx * 2 + 1];
      int i0 = scrI[tx * 2], i1 = scrI[tx * 2 + 1];
      stok4[tx] = (v1 > v0 || (v1 == v0 && i1 < i0)) ? i1 : i0;
    }
  } else {
    if (tx < 4) stok4[tx] = START_TOK;
  }
  __syncthreads();
  // stage embed
#pragma unroll
  for (int k = 0; k < 2; ++k) {
    const int idx = k * NTHR + tx;
    const int bb = idx >> 8, e = idx & 255;
    sacts[bb * 768 + e] = p.embed[(size_t)stok4[bb] * E_ + e];
  }
  __syncthreads();
  // GRU0 gates
  const int u = tx >> 5, l = tx & 31;
  const int j = ug * 16 + u;
  {
    float red[16];
#pragma unroll
    for (int q = 0; q < 16; ++q) red[q] = 0.f;
#pragma unroll
    for (int g = 0; g < 3; ++g) {
      const float4* wx = (const float4*)(p.Wih0 + (size_t)(g * H_ + j) * 768);
      float* dx = (g < 2) ? &red[g * 4] : &red[8];
#pragma unroll
      for (int c = 0; c < 6; ++c) {
        float4 w = wx[l + 32 * c];
#pragma unroll
        for (int b2 = 0; b2 < 4; ++b2) {
          const float* a = &sacts[b2 * 768 + 4 * l + 128 * c];
          dx[b2] = fmaf(w.x, a[0], dx[b2]); dx[b2] = fmaf(w.y, a[1], dx[b2]);
          dx[b2] = fmaf(w.z, a[2], dx[b2]); dx[b2] = fmaf(w.w, a[3], dx[b2]);
        }
      }
      const float4* wh = (const float4*)(p.Whh0 + (size_t)(g * H_ + j) * H_);
      float* dh = (g < 2) ? &red[g * 4] : &red[12];
#pragma unroll
      for (int c = 0; c < 4; ++c) {
        float4 w = wh[l + 32 * c];
#pragma unroll
        for (int b2 = 0; b2 < 4; ++b2) {
          const float* a = &sh0l[b2 * 512 + 4 * l + 128 * c];
          dh[b2] = fmaf(w.x, a[0], dh[b2]); dh[b2] = fmaf(w.y, a[1], dh[b2]);
          dh[b2] = fmaf(w.z, a[2], dh[b2]); dh[b2] = fmaf(w.w, a[3], dh[b2]);
        }
      }
    }
#pragma unroll
    for (int d = 1; d < 32; d <<= 1)
#pragma unroll
      for (int q = 0; q < 16; ++q) red[q] += __shfl_xor(red[q], d);
    if (l < 4) {
      const float rr = sigf(red[l] + p.bih0[j] + p.bhh0[j]);
      const float zz = sigf(red[4 + l] + p.bih0[H_ + j] + p.bhh0[H_ + j]);
      const float nn = tanhf(red[8 + l] + p.bih0[2 * H_ + j] +
                             rr * (red[12 + l] + p.bhh0[2 * H_ + j]));
      const float hp = sh0l[l * 512 + j];
      // sc0 store: must be visible to the 32 same-bg blocks after the rendezvous
      st_cf(wsf + OFF_H0 + (size_t)(1 - par) * BH + (size_t)(b4 + l) * H_ + j,
            (1.f - zz) * nn + zz * hp);
    }
  }
  // ---------------- bg-local 32-way rendezvous on h0 ----------------
  asm volatile("s_waitcnt vmcnt(0)" ::: "memory");
  __syncthreads();
  {
    unsigned* cnt = (unsigned*)wsf + OFF_SYNC + bg * 128 + t;
    if (tx == 0) {
      __hip_atomic_fetch_add(cnt, 1u, __ATOMIC_RELAXED, __HIP_MEMORY_SCOPE_AGENT);
      while (ld_cu(cnt) < 32u) __builtin_amdgcn_s_sleep(1);
    }
  }
  __syncthreads();
  // ---------------- phase 2: stage h0_new (sc0), GRU1 gates ----------------
  {
    const ull* pX = (const ull*)(wsf + OFF_H0 + (size_t)(1 - par) * BH);
    ull vx[2];
#pragma unroll
    for (int k = 0; k < 2; ++k) {
      const int iu = k * NTHR + tx;
      const int bb = iu >> 8, cc = iu & 255;
      const ull* a1 = pX + (size_t)(b4 + bb) * 256 + cc;
      asm volatile("global_load_dwordx2 %0, %1, off sc0 sc1" : "=v"(vx[k]) : "v"(a1));
    }
    asm volatile("s_waitcnt vmcnt(0)" ::: "memory");
#pragma unroll
    for (int k = 0; k < 2; ++k) {
      const int iu = k * NTHR + tx;
      const int bb = iu >> 8, cc = iu & 255;
      *(ull*)&sx[bb * 512 + cc * 2] = vx[k];
    }
  }
  __syncthreads();
  {
    float red[16];
#pragma unroll
    for (int q = 0; q < 16; ++q) red[q] = 0.f;
#pragma unroll
    for (int g = 0; g < 3; ++g) {
      const float4* wx = (const float4*)(p.Wih1 + (size_t)(g * H_ + j) * H_);
      float* dx = (g < 2) ? &red[g * 4] : &red[8];
#pragma unroll
      for (int c = 0; c < 4; ++c) {
        float4 w = wx[l + 32 * c];
#pragma unroll
        for (int b2 = 0; b2 < 4; ++b2) {
          const float* a = &sx[b2 * 512 + 4 * l + 128 * c];
          dx[b2] = fmaf(w.x, a[0], dx[b2]); dx[b2] = fmaf(w.y, a[1], dx[b2]);
          dx[b2] = fmaf(w.z, a[2], dx[b2]); dx[b2] = fmaf(w.w, a[3], dx[b2]);
        }
      }
      const float4* wh = (const float4*)(p.Whh1 + (size_t)(g * H_ + j) * H_);
      float* dh = (g < 2) ? &red[g * 4] : &red[12];
#pragma unroll
      for (int c = 0; c < 4; ++c) {
        float4 w = wh[l + 32 * c];
#pragma unroll
        for (int b2 = 0; b2 < 4; ++b2) {
          const float* a = &sh1r[b2 * 512 + 4 * l + 128 * c];
          dh[b2] = fmaf(w.x, a[0], dh[b2]); dh[b2] = fmaf(w.y, a[1], dh[b2]);
          dh[b2] = fmaf(w.z, a[2], dh[b2]); dh[b2] = fmaf(w.w, a[3], dh[b2]);
        }
      }
    }
#pragma unroll
    for (int d = 1; d < 32; d <<= 1)
#pragma unroll
      for (int q = 0; q < 16; ++q) red[q] += __shfl_xor(red[q], d);
    if (l < 4) {
      const float rr = sigf(red[l] + p.bih1[j] + p.bhh1[j]);
      const float zz = sigf(red[4 + l] + p.bih1[H_ + j] + p.bhh1[H_ + j]);
      const float nn = tanhf(red[8 + l] + p.bih1[2 * H_ + j] +
                             rr * (red[12 + l] + p.bhh1[2 * H_ + j]));
      const float hp = sh1r[l * 512 + j];
      const float hnew = (1.f - zz) * nn + zz * hp;
      wsf[OFF_H1 + (size_t)(1 - par) * BH + (size_t)(b4 + l) * H_ + j] = hnew;  // plain
      hout[u * 4 + l] = hnew;
    }
  }
  __syncthreads();
  if (tx < 32) {   // bf16 pack (2 units / dword) -> h1bf[t] (plain)
    const int b2 = tx & 3, pp = tx >> 2;
    const float h0v = hout[(pp * 2) * 4 + b2];
    const float h1v = hout[(pp * 2 + 1) * 4 + b2];
    const unsigned pk = (unsigned)f2bf(h0v) | ((unsigned)f2bf(h1v) << 16);
    *(int*)(h1bf + ((size_t)t * B_ + b4 + b2) * H_ + ug * 16 + pp * 2) = (int)pk;
  }
}

// attention batch split over 6 blocks
__device__ __constant__ int AST[7] = {0, 6, 12, 17, 22, 27, 32};

// ---------------- per-step kernel 2: vocab scan + attention(t+1) ----------------
__global__ void __launch_bounds__(NTHR) k_scan(Params p, int t) {
  float* wsf = p.ws;
  const unsigned short* h1bf = (const unsigned short*)(wsf + OFF_H1BF);
  const unsigned short* wobf = (const unsigned short*)(wsf + OFF_WOBF);
  const int bk = blockIdx.x, tx = threadIdx.x;
  const int par = t & 1;
  __shared__ float scrF[8][16][4];
  __shared__ int   scrI2[8][16][2];
  __shared__ float wlds[S_];
  __shared__ float shsS;
  __shared__ float rv[NTHR];

  if (bk < ND) {
    const int v0 = bk * 128;
    const int w = tx >> 6, l = tx & 63, lr = l & 15, lq = l >> 4;
    const int vr = w * 16 + lr;
    const unsigned short* brow = wobf + (size_t)(v0 + vr) * H_ + lq * 8;
    for (int bt = 0; bt < 2; ++bt) {
      const unsigned short* arow = h1bf + ((size_t)t * B_ + bt * 16 + lr) * H_ + lq * 8;
      f32x4 acc = {0.f, 0.f, 0.f, 0.f};
#pragma unroll 4
      for (int kc = 0; kc < 16; ++kc) {
        bf16x8 a = *(const bf16x8*)(arow + kc * 32);
        bf16x8 bv = *(const bf16x8*)(brow + kc * 32);
        acc = __builtin_amdgcn_mfma_f32_16x16x32_bf16(a, bv, acc, 0, 0, 0);
      }
      const float bov = p.bo[v0 + vr];
#pragma unroll
      for (int r = 0; r < 4; ++r) {
        float v1 = acc[r] + bov, v2 = -3.0e38f;
        int i1 = v0 + vr, i2 = 0x7fffffff;
        float m = v1, s = 1.0f;
#pragma unroll
        for (int d = 1; d < 16; d <<= 1) {
          float w1 = __shfl_xor(v1, d); int j1 = __shfl_xor(i1, d);
          float w2 = __shfl_xor(v2, d); int j2 = __shfl_xor(i2, d);
          float m2 = __shfl_xor(m, d);  float s2 = __shfl_xor(s, d);
          if (w1 > v1 || (w1 == v1 && j1 < i1)) { v2 = v1; i2 = i1; v1 = w1; i1 = j1; }
          else if (w1 > v2 || (w1 == v2 && j1 < i2)) { v2 = w1; i2 = j1; }
          if (w2 > v2 || (w2 == v2 && j2 < i2)) {
            if (w2 > v1 || (w2 == v1 && j2 < i1)) { v2 = v1; i2 = i1; v1 = w2; i1 = j2; }
            else { v2 = w2; i2 = j2; }
          }
          lse_merge(m, s, m2, s2);
        }
        if (lr == 0) {
          const int bb = lq * 4 + r;
          scrF[w][bb][0] = v1; scrF[w][bb][1] = v2;
          scrF[w][bb][2] = m;  scrF[w][bb][3] = s;
          scrI2[w][bb][0] = i1; scrI2[w][bb][1] = i2;
        }
      }
      __syncthreads();
      if (tx < 16) {   // combine 8 waves; publish partials + argmax candidates
        float v1 = scrF[0][tx][0], v2 = scrF[0][tx][1];
        float m = scrF[0][tx][2], s = scrF[0][tx][3];
        int i1 = scrI2[0][tx][0], i2 = scrI2[0][tx][1];
#pragma unroll
        for (int ww = 1; ww < 8; ++ww) {
          float w1 = scrF[ww][tx][0]; int j1 = scrI2[ww][tx][0];
          float w2 = scrF[ww][tx][1]; int j2 = scrI2[ww][tx][1];
          if (w1 > v1 || (w1 == v1 && j1 < i1)) { v2 = v1; i2 = i1; v1 = w1; i1 = j1; }
          else if (w1 > v2 || (w1 == v2 && j1 < i2)) { v2 = w1; i2 = j1; }
          if (w2 > v2 || (w2 == v2 && j2 < i2)) {
            if (w2 > v1 || (w2 == v1 && j2 < i1)) { v2 = v1; i2 = i1; v1 = w2; i1 = j2; }
            else { v2 = w2; i2 = j2; }
          }
          lse_merge(m, s, scrF[ww][tx][2], scrF[ww][tx][3]);
        }
        const int b = bt * 16 + tx;
        const size_t cb = (size_t)(t * 32 + b);
        wsf[OFF_LSM + cb * 256 + bk] = m;
        wsf[OFF_LSS + cb * 256 + bk] = s;
        ull pk1 = packvi(v1, i1);
        ull* gm = (ull*)(wsf + OFF_GMAX) + cb * 8;
        ull old = __hip_atomic_fetch_max(gm, pk1, __ATOMIC_RELAXED,
                                         __HIP_MEMORY_SCOPE_AGENT);
        ull cur = old > pk1 ? old : pk1;
        float curv = unpackv(cur);
        int* ccp = (int*)wsf + OFF_CCNT + cb * 32;
        int* clp = (int*)wsf + OFF_CLST + cb * 64;
        if (v1 >= curv - DELTA) {
          int k = __hip_atomic_fetch_add(ccp, 1, __ATOMIC_RELAXED,
                                         __HIP_MEMORY_SCOPE_AGENT);
          if (k < 64) clp[k] = i1;
        }
        if (i2 != 0x7fffffff && v2 >= curv - DELTA) {
          int k = __hip_atomic_fetch_add(ccp, 1, __ATOMIC_RELAXED,
                                         __HIP_MEMORY_SCOPE_AGENT);
          if (k < 64) clp[k] = i2;
        }
      }
      __syncthreads();
    }
  } else if (t < T_ - 1) {       // attention for step t+1 using h1(t)
    const int q = bk - ND;
    for (int b = AST[q]; b < AST[q + 1]; ++b) {
      const float h1v = wsf[OFF_H1 + (size_t)(1 - par) * BH + (size_t)b * H_ + tx];
      rv[tx] = h1v * p.Wa[tx];
      __syncthreads();
      if (tx < 64) {
        float v = 0.f;
#pragma unroll
        for (int o = 0; o < 8; ++o) v += rv[tx + o * 64];
#pragma unroll
        for (int d = 1; d < 64; d <<= 1) v += __shfl_xor(v, d);
        if (tx == 0) shsS = v;
      }
      __syncthreads();
      if (tx < S_) {
        float sc = tanhf(shsS + wsf[OFF_CS + b * S_ + tx]);
        float e = expf(sc); float sum = e;
#pragma unroll
        for (int d = 1; d < 64; d <<= 1) sum += __shfl_xor(sum, d);
        float w2 = e / sum; wlds[tx] = w2;
        p.out[(size_t)B_ * T_ * V_ + ((size_t)b * T_ + (t + 1)) * S_ + tx] = w2;
      }
      __syncthreads();
      float a0 = 0.f;
      const float* cb = p.ctx + (size_t)b * S_ * C_ + tx;
#pragma unroll 8
      for (int s2 = 0; s2 < S_; ++s2) a0 = fmaf(wlds[s2], cb[(size_t)s2 * C_], a0);
      wsf[OFF_ATT + (size_t)b * H_ + tx] = a0;
      __syncthreads();
    }
  }
}

// ---------------- deferred LSE reduction (all t,b) ----------------
__global__ void __launch_bounds__(256) lse_all(float* __restrict__ wsf) {
  const int id = blockIdx.x, tx = threadIdx.x;   // id = t*32+b
  __shared__ float rm[256], rs[256];
  rm[tx] = (tx < ND) ? wsf[OFF_LSM + (size_t)id * 256 + tx] : -3.0e38f;
  rs[tx] = (tx < ND) ? wsf[OFF_LSS + (size_t)id * 256 + tx] : 0.f;
  __syncthreads();
  if (tx < 64) {
    float m = rm[tx], s = rs[tx];
#pragma unroll
    for (int o = 64; o < 256; o += 64) lse_merge(m, s, rm[tx + o], rs[tx + o]);
#pragma unroll
    for (int d = 1; d < 64; d <<= 1) {
      float m2 = __shfl_xor(m, d), s2 = __shfl_xor(s, d);
      lse_merge(m, s, m2, s2);
    }
    if (tx == 0) wsf[OFF_LSEA + id] = m + logf(s);
  }
}

// ---------------- final batched logp GEMM (bf16 MFMA, nt stores) ----------------
__global__ void __launch_bounds__(256) gemm_logp(const unsigned short* __restrict__ h1bf,
                                                 const unsigned short* __restrict__ wobf,
                                                 const float* __restrict__ bo,
                                                 const float* __restrict__ lsea,
                                                 float* __restrict__ out) {
  __shared__ __align__(16) unsigned short As[2][128 * 40];  // rows padded to 80B
  __shared__ __align__(16) unsigned short Bs[2][128 * 40];
  const int tx = threadIdx.x;
  const int v0 = blockIdx.x * 128, m0 = blockIdx.y * 128;
  const int w = tx >> 6, l = tx & 63;
  const int wm = w >> 1, wn = w & 1;
  f32x4 acc[4][4];
#pragma unroll
  for (int i = 0; i < 4; ++i)
#pragma unroll
    for (int j = 0; j < 4; ++j) acc[i][j] = (f32x4){0.f, 0.f, 0.f, 0.f};

#define GSTAGE(ci, kc) {                                                        \
    _Pragma("unroll")                                                           \
    for (int e = 0; e < 2; ++e) {                                               \
      const int seg = tx * 2 + e, row = seg >> 2, s = seg & 3;                  \
      *(uint4*)&As[ci][row * 40 + s * 8] =                                      \
          *(const uint4*)(h1bf + (size_t)(m0 + row) * H_ + (kc) * 32 + s * 8);  \
      *(uint4*)&Bs[ci][row * 40 + s * 8] =                                      \
          *(const uint4*)(wobf + (size_t)(v0 + row) * H_ + (kc) * 32 + s * 8);  \
    } }

  GSTAGE(0, 0);
  __syncthreads();
  for (int kc = 0; kc < 16; ++kc) {
    const int cur = kc & 1;
    if (kc < 15) GSTAGE(cur ^ 1, kc + 1);
    const int lk = (l >> 4) * 8, lr = l & 15;
    bf16x8 af[4], bf[4];
#pragma unroll
    for (int f = 0; f < 4; ++f) {
      af[f] = *(const bf16x8*)&As[cur][(wm * 64 + f * 16 + lr) * 40 + lk];
      bf[f] = *(const bf16x8*)&Bs[cur][(wn * 64 + f * 16 + lr) * 40 + lk];
    }
#pragma unroll
    for (int fm = 0; fm < 4; ++fm)
#pragma unroll
      for (int fn = 0; fn < 4; ++fn)
        acc[fm][fn] = __builtin_amdgcn_mfma_f32_16x16x32_bf16(af[fm], bf[fn], acc[fm][fn], 0, 0, 0);
    __syncthreads();
  }
#undef GSTAGE
  const int lr = l & 15, lq = l >> 4;
#pragma unroll
  for (int fm = 0; fm < 4; ++fm) {
#pragma unroll
    for (int fn = 0; fn < 4; ++fn) {
      const int v = v0 + wn * 64 + fn * 16 + lr;
      const float bov = bo[v];
#pragma unroll
      for (int r = 0; r < 4; ++r) {
        const int M = m0 + wm * 64 + fm * 16 + lq * 4 + r;
        const int tt = M >> 5, b = M & 31;
        __builtin_nontemporal_store(acc[fm][fn][r] + bov - lsea[tt * B_ + b],
                                    &out[((size_t)b * T_ + tt) * (size_t)V_ + v]);
      }
    }
  }
}

// ---------------- host launch ----------------
extern "C" void kernel_launch(void* const* d_in, const int* in_sizes, int n_in,
                              void* d_out, int out_size, void* d_ws, size_t ws_size,
                              hipStream_t stream) {
  (void)in_sizes; (void)n_in; (void)out_size;
  if (ws_size < (size_t)WS_FLOATS * sizeof(float)) return;  // workspace too small

  const float* ctx   = (const float*)d_in[0];
  // d_in[1] = max_len (scalar, == 32, hardcoded)
  const float* embed = (const float*)d_in[2];
  const float* Wa    = (const float*)d_in[3];
  const float* ba    = (const float*)d_in[4];
  const float* Wih0  = (const float*)d_in[5];
  const float* Whh0  = (const float*)d_in[6];
  const float* bih0  = (const float*)d_in[7];
  const float* bhh0  = (const float*)d_in[8];
  const float* Wih1  = (const float*)d_in[9];
  const float* Whh1  = (const float*)d_in[10];
  const float* bih1  = (const float*)d_in[11];
  const float* bhh1  = (const float*)d_in[12];
  const float* Wo    = (const float*)d_in[13];
  const float* bo    = (const float*)d_in[14];
  float* ws  = (float*)d_ws;
  float* out = (float*)d_out;

  zero_k<<<dim3(256), dim3(256), 0, stream>>>(ws);
  cscore_k<<<dim3(32), dim3(256), 0, stream>>>(ctx, Wa, ba, ws);
  cvt_wobf<<<dim3(16000), dim3(256), 0, stream>>>(Wo, (unsigned short*)(ws + OFF_WOBF));
  attn0_k<<<dim3(32), dim3(NTHR), 0, stream>>>(ctx, ws, out);

  Params p;
  p.ctx = ctx; p.embed = embed; p.Wa = Wa;
  p.Wih0 = Wih0; p.Whh0 = Whh0; p.bih0 = bih0; p.bhh0 = bhh0;
  p.Wih1 = Wih1; p.Whh1 = Whh1; p.bih1 = bih1; p.bhh1 = bhh1;
  p.Wo = Wo; p.bo = bo; p.ws = ws; p.out = out;

  for (int t = 0; t < T_; ++t) {
    k_gru01<<<dim3(256), dim3(NTHR), 0, stream>>>(p, t);
    k_scan<<<dim3(256), dim3(NTHR), 0, stream>>>(p, t);
  }

  lse_all<<<dim3(1024), dim3(256), 0, stream>>>(ws);
  gemm_logp<<<dim3(250, 8), dim3(256), 0, stream>>>(
      (const unsigned short*)(ws + OFF_H1BF), (const unsigned short*)(ws + OFF_WOBF),
      bo, ws + OFF_LSEA, out);
}

// Round 12
// 2084.366 us; speedup vs baseline: 2.5239x; 1.2440x over previous
//
#include <hip/hip_runtime.h>

// ---------------- problem constants ----------------
#define B_ 32
#define S_ 64
#define C_ 512
#define E_ 256
#define H_ 512
#define V_ 32000
#define T_ 32
#define NTHR 512
#define ND 250         // scan blocks (250*128 = 32000); blocks 250..255 = attention
#define START_TOK 1
#define DELTA 0.05f    // candidate window (bf16 logit err sigma ~6e-4)
#define BH (B_ * H_)

// ---------------- workspace layout (float offsets) ----------------
#define OFF_CS   0          // cscore[32][64] = 2048
#define OFF_LSEA 2048       // lse[32 t][32 b] = 1024
#define OFF_A2V  3072       // float [1024 cb][512] per-block top2 values = 524288
#define OFF_A2I  527360     // int   [1024 cb][512] per-block top2 indices = 524288
#define OFF_LSM  1051648    // float [1024][256] = 262144
#define OFF_LSS  1313792    // float [1024][256] = 262144
#define OFF_ATT  1575936    // attend [32][512] = 16384
#define OFF_H0   1592320    // h0[2][32][512] = 32768
#define OFF_H1   1625088    // h1[2][32][512] = 32768
#define OFF_H1BF 1657856    // history ushort[1024][512] = 262144 f
#define OFF_WOBF 1920000    // ushort[32000][512] bf16 Wo = 8192000 f
#define OFF_SYNC 10112000   // int cnt[8 bg][128] (slot t) = 1024
#define WS_FLOATS 10113024  // ~40.5 MB

typedef unsigned long long ull;
typedef __attribute__((ext_vector_type(8))) short bf16x8;
typedef __attribute__((ext_vector_type(4))) float f32x4;

struct Params {
  const float* ctx; const float* embed; const float* Wa;
  const float* Wih0; const float* Whh0; const float* bih0; const float* bhh0;
  const float* Wih1; const float* Whh1; const float* bih1; const float* bhh1;
  const float* Wo; const float* bo;
  float* ws; float* out;
};

__device__ __forceinline__ float sigf(float x) { return 1.0f / (1.0f + expf(-x)); }

__device__ __forceinline__ unsigned short f2bf(float f) {  // RNE f32->bf16
  unsigned u = __builtin_bit_cast(unsigned, f);
  unsigned r = (u + 0x7FFFu + ((u >> 16) & 1u)) >> 16;
  return (unsigned short)r;
}

__device__ __forceinline__ void lse_merge(float& m, float& s, float m2, float s2) {
  float M = fmaxf(m, m2);
  s = s * expf(m - M) + s2 * expf(m2 - M);
  m = M;
}

// ---- coherent (L2-bypass) ops only for the intra-kernel h0 handoff ----
__device__ __forceinline__ void st_cf(float* p, float v) {
  __hip_atomic_store(p, v, __ATOMIC_RELAXED, __HIP_MEMORY_SCOPE_AGENT);
}
__device__ __forceinline__ unsigned ld_cu(const unsigned* p) {
  return __hip_atomic_load(p, __ATOMIC_RELAXED, __HIP_MEMORY_SCOPE_AGENT);
}

// ---------------- prologue kernels ----------------
__global__ void __launch_bounds__(256) zero_k(float* wsf) {
  const unsigned i = blockIdx.x * 256u + threadIdx.x;
  if (i < 524288u) {
    wsf[OFF_A2V + i] = -3.0e38f;
    ((int*)wsf)[OFF_A2I + i] = 0x7fffffff;
  }
  if (i < 65536u) wsf[OFF_H0 + i] = 0.0f;               // h0[2] + h1[2]
  if (i < 1024u) ((unsigned*)wsf)[OFF_SYNC + i] = 0u;   // bg-sync counters
}

__global__ void __launch_bounds__(256) cscore_k(const float* __restrict__ ctx,
                                                const float* __restrict__ Wa,
                                                const float* __restrict__ ba,
                                                float* __restrict__ wsf) {
  const int b = blockIdx.x;
  const int s = threadIdx.x >> 2, q = threadIdx.x & 3;
  const float* cp = ctx + ((size_t)b * S_ + s) * C_ + q * 128;
  const float* wp = Wa + H_ + q * 128;     // context half of Wa
  float acc = 0.f;
#pragma unroll 8
  for (int k = 0; k < 128; ++k) acc = fmaf(cp[k], wp[k], acc);
  acc += __shfl_xor(acc, 1);
  acc += __shfl_xor(acc, 2);
  if (q == 0) wsf[OFF_CS + b * S_ + s] = acc + ba[0];
}

__global__ void __launch_bounds__(256) cvt_wobf(const float* __restrict__ wo,
                                                unsigned short* __restrict__ dst) {
  const size_t i = ((size_t)blockIdx.x * 256u + threadIdx.x) * 4;
  float4 v = *(const float4*)(wo + i);
  ushort4 o;
  o.x = f2bf(v.x); o.y = f2bf(v.y); o.z = f2bf(v.z); o.w = f2bf(v.w);
  *(ushort4*)(dst + i) = o;
}

// attention for t=0 (h1 = 0 -> hscore = 0)
__global__ void __launch_bounds__(NTHR) attn0_k(const float* __restrict__ ctx,
                                                float* __restrict__ wsf,
                                                float* __restrict__ out) {
  const int b = blockIdx.x, tx = threadIdx.x;
  __shared__ float wlds[S_];
  if (tx < S_) {
    float sc = tanhf(wsf[OFF_CS + b * S_ + tx]);
    float e = expf(sc); float sum = e;
#pragma unroll
    for (int d = 1; d < 64; d <<= 1) sum += __shfl_xor(sum, d);
    float w = e / sum; wlds[tx] = w;
    out[(size_t)B_ * T_ * V_ + ((size_t)b * T_ + 0) * S_ + tx] = w;
  }
  __syncthreads();
  float a0 = 0.f;
  const float* cb = ctx + (size_t)b * S_ * C_ + tx;
#pragma unroll 8
  for (int s2 = 0; s2 < S_; ++s2) a0 = fmaf(wlds[s2], cb[(size_t)s2 * C_], a0);
  wsf[OFF_ATT + (size_t)b * H_ + tx] = a0;
}

// ======== fused per-step kernel 1: resolve + embed + GRU0 | bg-sync | GRU1 ========
__global__ void __launch_bounds__(NTHR) k_gru01(Params p, int t) {
  float* wsf = p.ws;
  unsigned short* h1bf = (unsigned short*)(wsf + OFF_H1BF);
  const int bk = blockIdx.x, tx = threadIdx.x;
  const int ug = bk & 31, bg = bk >> 5, b4 = bg * 4;
  const int par = t & 1;
  __shared__ __align__(16) float sacts[4 * 768];
  __shared__ __align__(16) float sh0l[4 * 512];
  __shared__ __align__(16) float sh1r[4 * 512];   // h1_prev (resolve + GRU1)
  __shared__ __align__(16) float sx[4 * 512];     // h0_new (phase 2)
  __shared__ int   stok4[4];
  __shared__ float scrV[8];
  __shared__ int   scrI[8];
  __shared__ float scrM[8];
  __shared__ int   slist4[4][16];
  __shared__ int   scnt4[4];
  __shared__ float hout[64];

  // ---------------- phase 1: stage (plain cached loads) ----------------
  {
    const int bb = tx >> 7, cc = (tx & 127) * 4;
    float4 va = *(const float4*)(wsf + OFF_ATT + (size_t)(b4 + bb) * H_ + cc);
    float4 vh = *(const float4*)(wsf + OFF_H0 + (size_t)par * BH + (size_t)(b4 + bb) * H_ + cc);
    float4 vr = *(const float4*)(wsf + OFF_H1 + (size_t)par * BH + (size_t)(b4 + bb) * H_ + cc);
    *(float4*)&sacts[bb * 768 + 256 + cc] = va;
    *(float4*)&sh0l[bb * 512 + cc] = vh;
    *(float4*)&sh1r[bb * 512 + cc] = vr;
  }
  __syncthreads();
  // --- resolve tokens: scan per-block top2 slots, refine within DELTA window ---
  if (t > 0) {
    const int w = tx >> 6, lane = tx & 63;
    const int lb = w >> 1, ws2 = w & 1, b = b4 + lb;
    const int gtx = tx & 127;
    const size_t cb_ = (size_t)(t - 1) * 32 + b;
    const float* avp = wsf + OFF_A2V + cb_ * 512;
    const int*   aip = (const int*)wsf + OFF_A2I + cb_ * 512;
    float v[4]; int id[4];
#pragma unroll
    for (int e = 0; e < 4; ++e) { v[e] = avp[gtx * 4 + e]; id[e] = aip[gtx * 4 + e]; }
    float M = fmaxf(fmaxf(v[0], v[1]), fmaxf(v[2], v[3]));
#pragma unroll
    for (int d = 1; d < 64; d <<= 1) M = fmaxf(M, __shfl_xor(M, d));
    if (lane == 0) scrM[w] = M;
    if (tx < 4) scnt4[tx] = 0;
    __syncthreads();
    M = fmaxf(scrM[lb * 2], scrM[lb * 2 + 1]);
#pragma unroll
    for (int e = 0; e < 4; ++e) {
      if (v[e] >= M - DELTA && id[e] != 0x7fffffff) {
        int k = atomicAdd(&scnt4[lb], 1);
        if (k < 16) slist4[lb][k] = id[e];
      }
    }
    __syncthreads();
    const int nc = min(scnt4[lb], 16);
    float bV = -3.0e38f; int bI = 0x7fffffff;
    for (int c = ws2; c < nc; c += 2) {
      const int idx = slist4[lb][c];
      const float* wr = p.Wo + (size_t)idx * H_ + lane * 8;
      const float* hr = sh1r + lb * 512 + lane * 8;
      float a = 0.f;
#pragma unroll
      for (int e = 0; e < 8; ++e) a = fmaf(hr[e], wr[e], a);
#pragma unroll
      for (int d = 1; d < 64; d <<= 1) a += __shfl_xor(a, d);
      a += p.bo[idx];
      if (a > bV || (a == bV && idx < bI)) { bV = a; bI = idx; }
    }
    if (lane == 0) { scrV[w] = bV; scrI[w] = bI; }
    __syncthreads();
    if (tx < 4) {
      float v0 = scrV[tx * 2], v1 = scrV[tx * 2 + 1];
      int i0 = scrI[tx * 2], i1 = scrI[tx * 2 + 1];
      stok4[tx] = (v1 > v0 || (v1 == v0 && i1 < i0)) ? i1 : i0;
    }
  } else {
    if (tx < 4) stok4[tx] = START_TOK;
  }
  __syncthreads();
  // stage embed
#pragma unroll
  for (int k = 0; k < 2; ++k) {
    const int idx = k * NTHR + tx;
    const int bb = idx >> 8, e = idx & 255;
    sacts[bb * 768 + e] = p.embed[(size_t)stok4[bb] * E_ + e];
  }
  __syncthreads();
  // GRU0 gates
  const int u = tx >> 5, l = tx & 31;
  const int j = ug * 16 + u;
  {
    float red[16];
#pragma unroll
    for (int q = 0; q < 16; ++q) red[q] = 0.f;
#pragma unroll
    for (int g = 0; g < 3; ++g) {
      const float4* wx = (const float4*)(p.Wih0 + (size_t)(g * H_ + j) * 768);
      float* dx = (g < 2) ? &red[g * 4] : &red[8];
#pragma unroll
      for (int c = 0; c < 6; ++c) {
        float4 w = wx[l + 32 * c];
#pragma unroll
        for (int b2 = 0; b2 < 4; ++b2) {
          const float* a = &sacts[b2 * 768 + 4 * l + 128 * c];
          dx[b2] = fmaf(w.x, a[0], dx[b2]); dx[b2] = fmaf(w.y, a[1], dx[b2]);
          dx[b2] = fmaf(w.z, a[2], dx[b2]); dx[b2] = fmaf(w.w, a[3], dx[b2]);
        }
      }
      const float4* wh = (const float4*)(p.Whh0 + (size_t)(g * H_ + j) * H_);
      float* dh = (g < 2) ? &red[g * 4] : &red[12];
#pragma unroll
      for (int c = 0; c < 4; ++c) {
        float4 w = wh[l + 32 * c];
#pragma unroll
        for (int b2 = 0; b2 < 4; ++b2) {
          const float* a = &sh0l[b2 * 512 + 4 * l + 128 * c];
          dh[b2] = fmaf(w.x, a[0], dh[b2]); dh[b2] = fmaf(w.y, a[1], dh[b2]);
          dh[b2] = fmaf(w.z, a[2], dh[b2]); dh[b2] = fmaf(w.w, a[3], dh[b2]);
        }
      }
    }
#pragma unroll
    for (int d = 1; d < 32; d <<= 1)
#pragma unroll
      for (int q = 0; q < 16; ++q) red[q] += __shfl_xor(red[q], d);
    if (l < 4) {
      const float rr = sigf(red[l] + p.bih0[j] + p.bhh0[j]);
      const float zz = sigf(red[4 + l] + p.bih0[H_ + j] + p.bhh0[H_ + j]);
      const float nn = tanhf(red[8 + l] + p.bih0[2 * H_ + j] +
                             rr * (red[12 + l] + p.bhh0[2 * H_ + j]));
      const float hp = sh0l[l * 512 + j];
      // sc0 store: visible to the 32 same-bg blocks after the rendezvous
      st_cf(wsf + OFF_H0 + (size_t)(1 - par) * BH + (size_t)(b4 + l) * H_ + j,
            (1.f - zz) * nn + zz * hp);
    }
  }
  // ---------------- bg-local 32-way rendezvous on h0 ----------------
  asm volatile("s_waitcnt vmcnt(0)" ::: "memory");
  __syncthreads();
  {
    unsigned* cnt = (unsigned*)wsf + OFF_SYNC + bg * 128 + t;
    if (tx == 0) {
      __hip_atomic_fetch_add(cnt, 1u, __ATOMIC_RELAXED, __HIP_MEMORY_SCOPE_AGENT);
      while (ld_cu(cnt) < 32u) __builtin_amdgcn_s_sleep(1);
    }
  }
  __syncthreads();
  // ---------------- phase 2: stage h0_new (sc0), GRU1 gates ----------------
  {
    const ull* pX = (const ull*)(wsf + OFF_H0 + (size_t)(1 - par) * BH);
    ull vx[2];
#pragma unroll
    for (int k = 0; k < 2; ++k) {
      const int iu = k * NTHR + tx;
      const int bb = iu >> 8, cc = iu & 255;
      const ull* a1 = pX + (size_t)(b4 + bb) * 256 + cc;
      asm volatile("global_load_dwordx2 %0, %1, off sc0 sc1" : "=v"(vx[k]) : "v"(a1));
    }
    asm volatile("s_waitcnt vmcnt(0)" ::: "memory");
#pragma unroll
    for (int k = 0; k < 2; ++k) {
      const int iu = k * NTHR + tx;
      const int bb = iu >> 8, cc = iu & 255;
      *(ull*)&sx[bb * 512 + cc * 2] = vx[k];
    }
  }
  __syncthreads();
  {
    float red[16];
#pragma unroll
    for (int q = 0; q < 16; ++q) red[q] = 0.f;
#pragma unroll
    for (int g = 0; g < 3; ++g) {
      const float4* wx = (const float4*)(p.Wih1 + (size_t)(g * H_ + j) * H_);
      float* dx = (g < 2) ? &red[g * 4] : &red[8];
#pragma unroll
      for (int c = 0; c < 4; ++c) {
        float4 w = wx[l + 32 * c];
#pragma unroll
        for (int b2 = 0; b2 < 4; ++b2) {
          const float* a = &sx[b2 * 512 + 4 * l + 128 * c];
          dx[b2] = fmaf(w.x, a[0], dx[b2]); dx[b2] = fmaf(w.y, a[1], dx[b2]);
          dx[b2] = fmaf(w.z, a[2], dx[b2]); dx[b2] = fmaf(w.w, a[3], dx[b2]);
        }
      }
      const float4* wh = (const float4*)(p.Whh1 + (size_t)(g * H_ + j) * H_);
      float* dh = (g < 2) ? &red[g * 4] : &red[12];
#pragma unroll
      for (int c = 0; c < 4; ++c) {
        float4 w = wh[l + 32 * c];
#pragma unroll
        for (int b2 = 0; b2 < 4; ++b2) {
          const float* a = &sh1r[b2 * 512 + 4 * l + 128 * c];
          dh[b2] = fmaf(w.x, a[0], dh[b2]); dh[b2] = fmaf(w.y, a[1], dh[b2]);
          dh[b2] = fmaf(w.z, a[2], dh[b2]); dh[b2] = fmaf(w.w, a[3], dh[b2]);
        }
      }
    }
#pragma unroll
    for (int d = 1; d < 32; d <<= 1)
#pragma unroll
      for (int q = 0; q < 16; ++q) red[q] += __shfl_xor(red[q], d);
    if (l < 4) {
      const float rr = sigf(red[l] + p.bih1[j] + p.bhh1[j]);
      const float zz = sigf(red[4 + l] + p.bih1[H_ + j] + p.bhh1[H_ + j]);
      const float nn = tanhf(red[8 + l] + p.bih1[2 * H_ + j] +
                             rr * (red[12 + l] + p.bhh1[2 * H_ + j]));
      const float hp = sh1r[l * 512 + j];
      const float hnew = (1.f - zz) * nn + zz * hp;
      wsf[OFF_H1 + (size_t)(1 - par) * BH + (size_t)(b4 + l) * H_ + j] = hnew;  // plain
      hout[u * 4 + l] = hnew;
    }
  }
  __syncthreads();
  if (tx < 32) {   // bf16 pack (2 units / dword) -> h1bf[t] (plain)
    const int b2 = tx & 3, pp = tx >> 2;
    const float h0v = hout[(pp * 2) * 4 + b2];
    const float h1v = hout[(pp * 2 + 1) * 4 + b2];
    const unsigned pk = (unsigned)f2bf(h0v) | ((unsigned)f2bf(h1v) << 16);
    *(int*)(h1bf + ((size_t)t * B_ + b4 + b2) * H_ + ug * 16 + pp * 2) = (int)pk;
  }
}

// attention batch split over 6 blocks
__device__ __constant__ int AST[7] = {0, 6, 12, 17, 22, 27, 32};

// ---------------- per-step kernel 2: vocab scan + attention(t+1) ----------------
__global__ void __launch_bounds__(NTHR) k_scan(Params p, int t) {
  float* wsf = p.ws;
  const unsigned short* h1bf = (const unsigned short*)(wsf + OFF_H1BF);
  const unsigned short* wobf = (const unsigned short*)(wsf + OFF_WOBF);
  const int bk = blockIdx.x, tx = threadIdx.x;
  const int par = t & 1;
  __shared__ float scrF[8][16][4];
  __shared__ int   scrI2[8][16][2];
  __shared__ float wlds[S_];
  __shared__ float shsS;
  __shared__ float rv[NTHR];

  if (bk < ND) {
    const int v0 = bk * 128;
    const int w = tx >> 6, l = tx & 63, lr = l & 15, lq = l >> 4;
    const int vr = w * 16 + lr;
    const unsigned short* brow = wobf + (size_t)(v0 + vr) * H_ + lq * 8;
    for (int bt = 0; bt < 2; ++bt) {
      const unsigned short* arow = h1bf + ((size_t)t * B_ + bt * 16 + lr) * H_ + lq * 8;
      f32x4 acc = {0.f, 0.f, 0.f, 0.f};
#pragma unroll 4
      for (int kc = 0; kc < 16; ++kc) {
        bf16x8 a = *(const bf16x8*)(arow + kc * 32);
        bf16x8 bv = *(const bf16x8*)(brow + kc * 32);
        acc = __builtin_amdgcn_mfma_f32_16x16x32_bf16(a, bv, acc, 0, 0, 0);
      }
      const float bov = p.bo[v0 + vr];
#pragma unroll
      for (int r = 0; r < 4; ++r) {
        float v1 = acc[r] + bov, v2 = -3.0e38f;
        int i1 = v0 + vr, i2 = 0x7fffffff;
        float m = v1, s = 1.0f;
#pragma unroll
        for (int d = 1; d < 16; d <<= 1) {
          float w1 = __shfl_xor(v1, d); int j1 = __shfl_xor(i1, d);
          float w2 = __shfl_xor(v2, d); int j2 = __shfl_xor(i2, d);
          float m2 = __shfl_xor(m, d);  float s2 = __shfl_xor(s, d);
          if (w1 > v1 || (w1 == v1 && j1 < i1)) { v2 = v1; i2 = i1; v1 = w1; i1 = j1; }
          else if (w1 > v2 || (w1 == v2 && j1 < i2)) { v2 = w1; i2 = j1; }
          if (w2 > v2 || (w2 == v2 && j2 < i2)) {
            if (w2 > v1 || (w2 == v1 && j2 < i1)) { v2 = v1; i2 = i1; v1 = w2; i1 = j2; }
            else { v2 = w2; i2 = j2; }
          }
          lse_merge(m, s, m2, s2);
        }
        if (lr == 0) {
          const int bb = lq * 4 + r;
          scrF[w][bb][0] = v1; scrF[w][bb][1] = v2;
          scrF[w][bb][2] = m;  scrF[w][bb][3] = s;
          scrI2[w][bb][0] = i1; scrI2[w][bb][1] = i2;
        }
      }
      __syncthreads();
      if (tx < 16) {   // combine 8 waves; publish top2 + lse partials (ALL PLAIN)
        float v1 = scrF[0][tx][0], v2 = scrF[0][tx][1];
        float m = scrF[0][tx][2], s = scrF[0][tx][3];
        int i1 = scrI2[0][tx][0], i2 = scrI2[0][tx][1];
#pragma unroll
        for (int ww = 1; ww < 8; ++ww) {
          float w1 = scrF[ww][tx][0]; int j1 = scrI2[ww][tx][0];
          float w2 = scrF[ww][tx][1]; int j2 = scrI2[ww][tx][1];
          if (w1 > v1 || (w1 == v1 && j1 < i1)) { v2 = v1; i2 = i1; v1 = w1; i1 = j1; }
          else if (w1 > v2 || (w1 == v2 && j1 < i2)) { v2 = w1; i2 = j1; }
          if (w2 > v2 || (w2 == v2 && j2 < i2)) {
            if (w2 > v1 || (w2 == v1 && j2 < i1)) { v2 = v1; i2 = i1; v1 = w2; i1 = j2; }
            else { v2 = w2; i2 = j2; }
          }
          lse_merge(m, s, scrF[ww][tx][2], scrF[ww][tx][3]);
        }
        const int b = bt * 16 + tx;
        const size_t cb = (size_t)(t * 32 + b);
        wsf[OFF_LSM + cb * 256 + bk] = m;
        wsf[OFF_LSS + cb * 256 + bk] = s;
        wsf[OFF_A2V + cb * 512 + bk * 2] = v1;
        wsf[OFF_A2V + cb * 512 + bk * 2 + 1] = v2;
        ((int*)wsf)[OFF_A2I + cb * 512 + bk * 2] = i1;
        ((int*)wsf)[OFF_A2I + cb * 512 + bk * 2 + 1] = i2;
      }
      __syncthreads();
    }
  } else if (t < T_ - 1) {       // attention for step t+1 using h1(t)
    const int q = bk - ND;
    for (int b = AST[q]; b < AST[q + 1]; ++b) {
      const float h1v = wsf[OFF_H1 + (size_t)(1 - par) * BH + (size_t)b * H_ + tx];
      rv[tx] = h1v * p.Wa[tx];
      __syncthreads();
      if (tx < 64) {
        float v = 0.f;
#pragma unroll
        for (int o = 0; o < 8; ++o) v += rv[tx + o * 64];
#pragma unroll
        for (int d = 1; d < 64; d <<= 1) v += __shfl_xor(v, d);
        if (tx == 0) shsS = v;
      }
      __syncthreads();
      if (tx < S_) {
        float sc = tanhf(shsS + wsf[OFF_CS + b * S_ + tx]);
        float e = expf(sc); float sum = e;
#pragma unroll
        for (int d = 1; d < 64; d <<= 1) sum += __shfl_xor(sum, d);
        float w2 = e / sum; wlds[tx] = w2;
        p.out[(size_t)B_ * T_ * V_ + ((size_t)b * T_ + (t + 1)) * S_ + tx] = w2;
      }
      __syncthreads();
      float a0 = 0.f;
      const float* cb = p.ctx + (size_t)b * S_ * C_ + tx;
#pragma unroll 8
      for (int s2 = 0; s2 < S_; ++s2) a0 = fmaf(wlds[s2], cb[(size_t)s2 * C_], a0);
      wsf[OFF_ATT + (size_t)b * H_ + tx] = a0;
      __syncthreads();
    }
  }
}

// ---------------- deferred LSE reduction (all t,b) ----------------
__global__ void __launch_bounds__(256) lse_all(float* __restrict__ wsf) {
  const int id = blockIdx.x, tx = threadIdx.x;   // id = t*32+b
  __shared__ float rm[256], rs[256];
  rm[tx] = (tx < ND) ? wsf[OFF_LSM + (size_t)id * 256 + tx] : -3.0e38f;
  rs[tx] = (tx < ND) ? wsf[OFF_LSS + (size_t)id * 256 + tx] : 0.f;
  __syncthreads();
  if (tx < 64) {
    float m = rm[tx], s = rs[tx];
#pragma unroll
    for (int o = 64; o < 256; o += 64) lse_merge(m, s, rm[tx + o], rs[tx + o]);
#pragma unroll
    for (int d = 1; d < 64; d <<= 1) {
      float m2 = __shfl_xor(m, d), s2 = __shfl_xor(s, d);
      lse_merge(m, s, m2, s2);
    }
    if (tx == 0) wsf[OFF_LSEA + id] = m + logf(s);
  }
}

// ---- final batched logp GEMM: Wo tile persistent in LDS, all 8 m-tiles/block ----
__global__ void __launch_bounds__(NTHR) gemm_logp(const unsigned short* __restrict__ h1bf,
                                                  const unsigned short* __restrict__ wobf,
                                                  const float* __restrict__ bo,
                                                  const float* __restrict__ lsea,
                                                  float* __restrict__ out) {
  __shared__ __align__(16) unsigned short Bs[128 * 520];  // 128 Wo rows, 520-short pitch
  const int tx = threadIdx.x;
  const int v0 = blockIdx.x * 128;
  const int w = tx >> 6, l = tx & 63;
  const int lr = l & 15, lq = l >> 4;

  // stage this block's 128 Wo rows once (read Wo exactly once per launch)
#pragma unroll
  for (int e = 0; e < 16; ++e) {
    const int idx = e * NTHR + tx;          // 0..8191 uint4s
    const int row = idx >> 6, c = idx & 63;
    *(uint4*)&Bs[row * 520 + c * 8] = *(const uint4*)(wobf + (size_t)(v0 + row) * H_ + c * 8);
  }
  __syncthreads();

  float bov[8];
#pragma unroll
  for (int fn = 0; fn < 8; ++fn) bov[fn] = bo[v0 + fn * 16 + lr];

  for (int m0 = 0; m0 < 8; ++m0) {
    f32x4 acc[8];
#pragma unroll
    for (int fn = 0; fn < 8; ++fn) acc[fn] = (f32x4){0.f, 0.f, 0.f, 0.f};
    const unsigned short* arow = h1bf + (size_t)(m0 * 128 + w * 16 + lr) * H_ + lq * 8;
    bf16x8 a_cur = *(const bf16x8*)(arow);
#pragma unroll
    for (int kc = 0; kc < 16; ++kc) {
      bf16x8 a_nxt;
      if (kc < 15) a_nxt = *(const bf16x8*)(arow + (kc + 1) * 32);
#pragma unroll
      for (int fn = 0; fn < 8; ++fn) {
        bf16x8 bv = *(const bf16x8*)&Bs[(fn * 16 + lr) * 520 + lq * 8 + kc * 32];
        acc[fn] = __builtin_amdgcn_mfma_f32_16x16x32_bf16(a_cur, bv, acc[fn], 0, 0, 0);
      }
      a_cur = a_nxt;
    }
    // epilogue for this m-tile
    float lse_r[4];
#pragma unroll
    for (int r = 0; r < 4; ++r) {
      const int M = m0 * 128 + w * 16 + lq * 4 + r;
      lse_r[r] = lsea[(M >> 5) * B_ + (M & 31)];
    }
#pragma unroll
    for (int fn = 0; fn < 8; ++fn) {
      const int v = v0 + fn * 16 + lr;
#pragma unroll
      for (int r = 0; r < 4; ++r) {
        const int M = m0 * 128 + w * 16 + lq * 4 + r;
        const int tt = M >> 5, b = M & 31;
        __builtin_nontemporal_store(acc[fn][r] + bov[fn] - lse_r[r],
                                    &out[((size_t)b * T_ + tt) * (size_t)V_ + v]);
      }
    }
  }
}

// ---------------- host launch ----------------
extern "C" void kernel_launch(void* const* d_in, const int* in_sizes, int n_in,
                              void* d_out, int out_size, void* d_ws, size_t ws_size,
                              hipStream_t stream) {
  (void)in_sizes; (void)n_in; (void)out_size;
  if (ws_size < (size_t)WS_FLOATS * sizeof(float)) return;  // workspace too small

  const float* ctx   = (const float*)d_in[0];
  // d_in[1] = max_len (scalar, == 32, hardcoded)
  const float* embed = (const float*)d_in[2];
  const float* Wa    = (const float*)d_in[3];
  const float* ba    = (const float*)d_in[4];
  const float* Wih0  = (const float*)d_in[5];
  const float* Whh0  = (const float*)d_in[6];
  const float* bih0  = (const float*)d_in[7];
  const float* bhh0  = (const float*)d_in[8];
  const float* Wih1  = (const float*)d_in[9];
  const float* Whh1  = (const float*)d_in[10];
  const float* bih1  = (const float*)d_in[11];
  const float* bhh1  = (const float*)d_in[12];
  const float* Wo    = (const float*)d_in[13];
  const float* bo    = (const float*)d_in[14];
  float* ws  = (float*)d_ws;
  float* out = (float*)d_out;

  zero_k<<<dim3(2048), dim3(256), 0, stream>>>(ws);
  cscore_k<<<dim3(32), dim3(256), 0, stream>>>(ctx, Wa, ba, ws);
  cvt_wobf<<<dim3(16000), dim3(256), 0, stream>>>(Wo, (unsigned short*)(ws + OFF_WOBF));
  attn0_k<<<dim3(32), dim3(NTHR), 0, stream>>>(ctx, ws, out);

  Params p;
  p.ctx = ctx; p.embed = embed; p.Wa = Wa;
  p.Wih0 = Wih0; p.Whh0 = Whh0; p.bih0 = bih0; p.bhh0 = bhh0;
  p.Wih1 = Wih1; p.Whh1 = Whh1; p.bih1 = bih1; p.bhh1 = bhh1;
  p.Wo = Wo; p.bo = bo; p.ws = ws; p.out = out;

  for (int t = 0; t < T_; ++t) {
    k_gru01<<<dim3(256), dim3(NTHR), 0, stream>>>(p, t);
    k_scan<<<dim3(256), dim3(NTHR), 0, stream>>>(p, t);
  }

  lse_all<<<dim3(1024), dim3(256), 0, stream>>>(ws);
  gemm_logp<<<dim3(250), dim3(NTHR), 0, stream>>>(
      (const unsigned short*)(ws + OFF_H1BF), (const unsigned short*)(ws + OFF_WOBF),
      bo, ws + OFF_LSEA, out);
}

// Round 13
// 1903.109 us; speedup vs baseline: 2.7643x; 1.0952x over previous
//
#include <hip/hip_runtime.h>

// ---------------- problem constants ----------------
#define B_ 32
#define S_ 64
#define C_ 512
#define E_ 256
#define H_ 512
#define V_ 32000
#define T_ 32
#define NTHR 512
#define ND 250         // scan blocks (250*128 = 32000); blocks 250..255 = attention
#define START_TOK 1
#define DELTA 0.05f    // candidate window (bf16 logit err sigma ~6e-4)
#define BH (B_ * H_)

// ---------------- workspace layout (float offsets) ----------------
#define OFF_CS   0          // cscore[32][64] = 2048
#define OFF_LSEA 2048       // lse[32 t][32 b] = 1024
#define OFF_A2V  3072       // float [1024 cb][512] per-block top2 values = 524288
#define OFF_A2I  527360     // int   [1024 cb][512] per-block top2 indices = 524288
#define OFF_LSM  1051648    // float [1024][256] = 262144
#define OFF_LSS  1313792    // float [1024][256] = 262144
#define OFF_ATT  1575936    // attend [32][512] = 16384
#define OFF_H0   1592320    // h0[2][32][512] = 32768
#define OFF_H1   1625088    // h1[2][32][512] = 32768
#define OFF_H1BF 1657856    // history ushort[1024][512] = 262144 f
#define OFF_WOBF 1920000    // ushort[32000][512] bf16 Wo = 8192000 f
#define OFF_SYNC 10112000   // int cnt[8 bg][128] (slot t) = 1024
#define WS_FLOATS 10113024  // ~40.5 MB

typedef unsigned long long ull;
typedef __attribute__((ext_vector_type(8))) short bf16x8;
typedef __attribute__((ext_vector_type(4))) float f32x4;

struct Params {
  const float* ctx; const float* embed; const float* Wa;
  const float* Wih0; const float* Whh0; const float* bih0; const float* bhh0;
  const float* Wih1; const float* Whh1; const float* bih1; const float* bhh1;
  const float* Wo; const float* bo;
  float* ws; float* out;
};

__device__ __forceinline__ float sigf(float x) { return 1.0f / (1.0f + expf(-x)); }

__device__ __forceinline__ unsigned short f2bf(float f) {  // RNE f32->bf16
  unsigned u = __builtin_bit_cast(unsigned, f);
  unsigned r = (u + 0x7FFFu + ((u >> 16) & 1u)) >> 16;
  return (unsigned short)r;
}

__device__ __forceinline__ void lse_merge(float& m, float& s, float m2, float s2) {
  float M = fmaxf(m, m2);
  s = s * expf(m - M) + s2 * expf(m2 - M);
  m = M;
}

// ---- coherent (L2-bypass) ops only for the intra-kernel h0 handoff ----
__device__ __forceinline__ void st_cf(float* p, float v) {
  __hip_atomic_store(p, v, __ATOMIC_RELAXED, __HIP_MEMORY_SCOPE_AGENT);
}
__device__ __forceinline__ unsigned ld_cu(const unsigned* p) {
  return __hip_atomic_load(p, __ATOMIC_RELAXED, __HIP_MEMORY_SCOPE_AGENT);
}

// ---------------- prologue kernels ----------------
__global__ void __launch_bounds__(256) zero_k(float* wsf) {
  const unsigned i = blockIdx.x * 256u + threadIdx.x;
  if (i < 524288u) {
    wsf[OFF_A2V + i] = -3.0e38f;
    ((int*)wsf)[OFF_A2I + i] = 0x7fffffff;
  }
  if (i < 65536u) wsf[OFF_H0 + i] = 0.0f;               // h0[2] + h1[2]
  if (i < 1024u) ((unsigned*)wsf)[OFF_SYNC + i] = 0u;   // bg-sync counters
}

__global__ void __launch_bounds__(256) cscore_k(const float* __restrict__ ctx,
                                                const float* __restrict__ Wa,
                                                const float* __restrict__ ba,
                                                float* __restrict__ wsf) {
  const int b = blockIdx.x;
  const int s = threadIdx.x >> 2, q = threadIdx.x & 3;
  const float* cp = ctx + ((size_t)b * S_ + s) * C_ + q * 128;
  const float* wp = Wa + H_ + q * 128;     // context half of Wa
  float acc = 0.f;
#pragma unroll 8
  for (int k = 0; k < 128; ++k) acc = fmaf(cp[k], wp[k], acc);
  acc += __shfl_xor(acc, 1);
  acc += __shfl_xor(acc, 2);
  if (q == 0) wsf[OFF_CS + b * S_ + s] = acc + ba[0];
}

__global__ void __launch_bounds__(256) cvt_wobf(const float* __restrict__ wo,
                                                unsigned short* __restrict__ dst) {
  const size_t i = ((size_t)blockIdx.x * 256u + threadIdx.x) * 4;
  float4 v = *(const float4*)(wo + i);
  ushort4 o;
  o.x = f2bf(v.x); o.y = f2bf(v.y); o.z = f2bf(v.z); o.w = f2bf(v.w);
  *(ushort4*)(dst + i) = o;
}

// attention for t=0 (h1 = 0 -> hscore = 0)
__global__ void __launch_bounds__(NTHR) attn0_k(const float* __restrict__ ctx,
                                                float* __restrict__ wsf,
                                                float* __restrict__ out) {
  const int b = blockIdx.x, tx = threadIdx.x;
  __shared__ float wlds[S_];
  if (tx < S_) {
    float sc = tanhf(wsf[OFF_CS + b * S_ + tx]);
    float e = expf(sc); float sum = e;
#pragma unroll
    for (int d = 1; d < 64; d <<= 1) sum += __shfl_xor(sum, d);
    float w = e / sum; wlds[tx] = w;
    out[(size_t)B_ * T_ * V_ + ((size_t)b * T_ + 0) * S_ + tx] = w;
  }
  __syncthreads();
  float a0 = 0.f;
  const float* cb = ctx + (size_t)b * S_ * C_ + tx;
#pragma unroll 8
  for (int s2 = 0; s2 < S_; ++s2) a0 = fmaf(wlds[s2], cb[(size_t)s2 * C_], a0);
  wsf[OFF_ATT + (size_t)b * H_ + tx] = a0;
}

// ======== fused per-step kernel 1: resolve + embed + GRU0 | bg-sync | GRU1 ========
__global__ void __launch_bounds__(NTHR) k_gru01(Params p, int t) {
  float* wsf = p.ws;
  unsigned short* h1bf = (unsigned short*)(wsf + OFF_H1BF);
  const int bk = blockIdx.x, tx = threadIdx.x;
  const int ug = bk & 31, bg = bk >> 5, b4 = bg * 4;
  const int par = t & 1;
  __shared__ __align__(16) float sacts[4 * 768];
  __shared__ __align__(16) float sh0l[4 * 512];
  __shared__ __align__(16) float sh1r[4 * 512];   // h1_prev (resolve + GRU1)
  __shared__ __align__(16) float sx[4 * 512];     // h0_new (phase 2)
  __shared__ int   stok4[4];
  __shared__ float scrV[8];
  __shared__ int   scrI[8];
  __shared__ float scrM[8];
  __shared__ int   slist4[4][16];
  __shared__ int   scnt4[4];
  __shared__ float hout[64];

  // ---------------- phase 1: stage (plain cached loads) ----------------
  {
    const int bb = tx >> 7, cc = (tx & 127) * 4;
    float4 va = *(const float4*)(wsf + OFF_ATT + (size_t)(b4 + bb) * H_ + cc);
    float4 vh = *(const float4*)(wsf + OFF_H0 + (size_t)par * BH + (size_t)(b4 + bb) * H_ + cc);
    float4 vr = *(const float4*)(wsf + OFF_H1 + (size_t)par * BH + (size_t)(b4 + bb) * H_ + cc);
    *(float4*)&sacts[bb * 768 + 256 + cc] = va;
    *(float4*)&sh0l[bb * 512 + cc] = vh;
    *(float4*)&sh1r[bb * 512 + cc] = vr;
  }
  __syncthreads();
  // --- resolve tokens: scan per-block top2 slots, refine within DELTA window ---
  if (t > 0) {
    const int w = tx >> 6, lane = tx & 63;
    const int lb = w >> 1, ws2 = w & 1, b = b4 + lb;
    const int gtx = tx & 127;
    const size_t cb_ = (size_t)(t - 1) * 32 + b;
    const float* avp = wsf + OFF_A2V + cb_ * 512;
    const int*   aip = (const int*)wsf + OFF_A2I + cb_ * 512;
    float v[4]; int id[4];
#pragma unroll
    for (int e = 0; e < 4; ++e) { v[e] = avp[gtx * 4 + e]; id[e] = aip[gtx * 4 + e]; }
    float M = fmaxf(fmaxf(v[0], v[1]), fmaxf(v[2], v[3]));
#pragma unroll
    for (int d = 1; d < 64; d <<= 1) M = fmaxf(M, __shfl_xor(M, d));
    if (lane == 0) scrM[w] = M;
    if (tx < 4) scnt4[tx] = 0;
    __syncthreads();
    M = fmaxf(scrM[lb * 2], scrM[lb * 2 + 1]);
#pragma unroll
    for (int e = 0; e < 4; ++e) {
      if (v[e] >= M - DELTA && id[e] != 0x7fffffff) {
        int k = atomicAdd(&scnt4[lb], 1);
        if (k < 16) slist4[lb][k] = id[e];
      }
    }
    __syncthreads();
    const int nc = min(scnt4[lb], 16);
    float bV = -3.0e38f; int bI = 0x7fffffff;
    for (int c = ws2; c < nc; c += 2) {
      const int idx = slist4[lb][c];
      const float* wr = p.Wo + (size_t)idx * H_ + lane * 8;
      const float* hr = sh1r + lb * 512 + lane * 8;
      float a = 0.f;
#pragma unroll
      for (int e = 0; e < 8; ++e) a = fmaf(hr[e], wr[e], a);
#pragma unroll
      for (int d = 1; d < 64; d <<= 1) a += __shfl_xor(a, d);
      a += p.bo[idx];
      if (a > bV || (a == bV && idx < bI)) { bV = a; bI = idx; }
    }
    if (lane == 0) { scrV[w] = bV; scrI[w] = bI; }
    __syncthreads();
    if (tx < 4) {
      float v0 = scrV[tx * 2], v1 = scrV[tx * 2 + 1];
      int i0 = scrI[tx * 2], i1 = scrI[tx * 2 + 1];
      stok4[tx] = (v1 > v0 || (v1 == v0 && i1 < i0)) ? i1 : i0;
    }
  } else {
    if (tx < 4) stok4[tx] = START_TOK;
  }
  __syncthreads();
  // stage embed
#pragma unroll
  for (int k = 0; k < 2; ++k) {
    const int idx = k * NTHR + tx;
    const int bb = idx >> 8, e = idx & 255;
    sacts[bb * 768 + e] = p.embed[(size_t)stok4[bb] * E_ + e];
  }
  __syncthreads();
  // GRU0 gates
  const int u = tx >> 5, l = tx & 31;
  const int j = ug * 16 + u;
  {
    float red[16];
#pragma unroll
    for (int q = 0; q < 16; ++q) red[q] = 0.f;
#pragma unroll
    for (int g = 0; g < 3; ++g) {
      const float4* wx = (const float4*)(p.Wih0 + (size_t)(g * H_ + j) * 768);
      float* dx = (g < 2) ? &red[g * 4] : &red[8];
#pragma unroll
      for (int c = 0; c < 6; ++c) {
        float4 w = wx[l + 32 * c];
#pragma unroll
        for (int b2 = 0; b2 < 4; ++b2) {
          const float* a = &sacts[b2 * 768 + 4 * l + 128 * c];
          dx[b2] = fmaf(w.x, a[0], dx[b2]); dx[b2] = fmaf(w.y, a[1], dx[b2]);
          dx[b2] = fmaf(w.z, a[2], dx[b2]); dx[b2] = fmaf(w.w, a[3], dx[b2]);
        }
      }
      const float4* wh = (const float4*)(p.Whh0 + (size_t)(g * H_ + j) * H_);
      float* dh = (g < 2) ? &red[g * 4] : &red[12];
#pragma unroll
      for (int c = 0; c < 4; ++c) {
        float4 w = wh[l + 32 * c];
#pragma unroll
        for (int b2 = 0; b2 < 4; ++b2) {
          const float* a = &sh0l[b2 * 512 + 4 * l + 128 * c];
          dh[b2] = fmaf(w.x, a[0], dh[b2]); dh[b2] = fmaf(w.y, a[1], dh[b2]);
          dh[b2] = fmaf(w.z, a[2], dh[b2]); dh[b2] = fmaf(w.w, a[3], dh[b2]);
        }
      }
    }
#pragma unroll
    for (int d = 1; d < 32; d <<= 1)
#pragma unroll
      for (int q = 0; q < 16; ++q) red[q] += __shfl_xor(red[q], d);
    if (l < 4) {
      const float rr = sigf(red[l] + p.bih0[j] + p.bhh0[j]);
      const float zz = sigf(red[4 + l] + p.bih0[H_ + j] + p.bhh0[H_ + j]);
      const float nn = tanhf(red[8 + l] + p.bih0[2 * H_ + j] +
                             rr * (red[12 + l] + p.bhh0[2 * H_ + j]));
      const float hp = sh0l[l * 512 + j];
      // sc0 store: visible to the 32 same-bg blocks after the rendezvous
      st_cf(wsf + OFF_H0 + (size_t)(1 - par) * BH + (size_t)(b4 + l) * H_ + j,
            (1.f - zz) * nn + zz * hp);
    }
  }
  // ---------------- bg-local 32-way rendezvous on h0 ----------------
  asm volatile("s_waitcnt vmcnt(0)" ::: "memory");
  __syncthreads();
  {
    unsigned* cnt = (unsigned*)wsf + OFF_SYNC + bg * 128 + t;
    if (tx == 0) {
      __hip_atomic_fetch_add(cnt, 1u, __ATOMIC_RELAXED, __HIP_MEMORY_SCOPE_AGENT);
      while (ld_cu(cnt) < 32u) __builtin_amdgcn_s_sleep(1);
    }
  }
  __syncthreads();
  // ---------------- phase 2: stage h0_new (sc0), GRU1 gates ----------------
  {
    const ull* pX = (const ull*)(wsf + OFF_H0 + (size_t)(1 - par) * BH);
    ull vx[2];
#pragma unroll
    for (int k = 0; k < 2; ++k) {
      const int iu = k * NTHR + tx;
      const int bb = iu >> 8, cc = iu & 255;
      const ull* a1 = pX + (size_t)(b4 + bb) * 256 + cc;
      asm volatile("global_load_dwordx2 %0, %1, off sc0 sc1" : "=v"(vx[k]) : "v"(a1));
    }
    asm volatile("s_waitcnt vmcnt(0)" ::: "memory");
#pragma unroll
    for (int k = 0; k < 2; ++k) {
      const int iu = k * NTHR + tx;
      const int bb = iu >> 8, cc = iu & 255;
      *(ull*)&sx[bb * 512 + cc * 2] = vx[k];
    }
  }
  __syncthreads();
  {
    float red[16];
#pragma unroll
    for (int q = 0; q < 16; ++q) red[q] = 0.f;
#pragma unroll
    for (int g = 0; g < 3; ++g) {
      const float4* wx = (const float4*)(p.Wih1 + (size_t)(g * H_ + j) * H_);
      float* dx = (g < 2) ? &red[g * 4] : &red[8];
#pragma unroll
      for (int c = 0; c < 4; ++c) {
        float4 w = wx[l + 32 * c];
#pragma unroll
        for (int b2 = 0; b2 < 4; ++b2) {
          const float* a = &sx[b2 * 512 + 4 * l + 128 * c];
          dx[b2] = fmaf(w.x, a[0], dx[b2]); dx[b2] = fmaf(w.y, a[1], dx[b2]);
          dx[b2] = fmaf(w.z, a[2], dx[b2]); dx[b2] = fmaf(w.w, a[3], dx[b2]);
        }
      }
      const float4* wh = (const float4*)(p.Whh1 + (size_t)(g * H_ + j) * H_);
      float* dh = (g < 2) ? &red[g * 4] : &red[12];
#pragma unroll
      for (int c = 0; c < 4; ++c) {
        float4 w = wh[l + 32 * c];
#pragma unroll
        for (int b2 = 0; b2 < 4; ++b2) {
          const float* a = &sh1r[b2 * 512 + 4 * l + 128 * c];
          dh[b2] = fmaf(w.x, a[0], dh[b2]); dh[b2] = fmaf(w.y, a[1], dh[b2]);
          dh[b2] = fmaf(w.z, a[2], dh[b2]); dh[b2] = fmaf(w.w, a[3], dh[b2]);
        }
      }
    }
#pragma unroll
    for (int d = 1; d < 32; d <<= 1)
#pragma unroll
      for (int q = 0; q < 16; ++q) red[q] += __shfl_xor(red[q], d);
    if (l < 4) {
      const float rr = sigf(red[l] + p.bih1[j] + p.bhh1[j]);
      const float zz = sigf(red[4 + l] + p.bih1[H_ + j] + p.bhh1[H_ + j]);
      const float nn = tanhf(red[8 + l] + p.bih1[2 * H_ + j] +
                             rr * (red[12 + l] + p.bhh1[2 * H_ + j]));
      const float hp = sh1r[l * 512 + j];
      const float hnew = (1.f - zz) * nn + zz * hp;
      wsf[OFF_H1 + (size_t)(1 - par) * BH + (size_t)(b4 + l) * H_ + j] = hnew;  // plain
      hout[u * 4 + l] = hnew;
    }
  }
  __syncthreads();
  if (tx < 32) {   // bf16 pack (2 units / dword) -> h1bf[t] (plain)
    const int b2 = tx & 3, pp = tx >> 2;
    const float h0v = hout[(pp * 2) * 4 + b2];
    const float h1v = hout[(pp * 2 + 1) * 4 + b2];
    const unsigned pk = (unsigned)f2bf(h0v) | ((unsigned)f2bf(h1v) << 16);
    *(int*)(h1bf + ((size_t)t * B_ + b4 + b2) * H_ + ug * 16 + pp * 2) = (int)pk;
  }
}

// attention batch split over 6 blocks
__device__ __constant__ int AST[7] = {0, 6, 12, 17, 22, 27, 32};

// ---------------- per-step kernel 2: vocab scan + attention(t+1) ----------------
__global__ void __launch_bounds__(NTHR) k_scan(Params p, int t) {
  float* wsf = p.ws;
  const unsigned short* h1bf = (const unsigned short*)(wsf + OFF_H1BF);
  const unsigned short* wobf = (const unsigned short*)(wsf + OFF_WOBF);
  const int bk = blockIdx.x, tx = threadIdx.x;
  const int par = t & 1;
  __shared__ float scrF[8][16][4];
  __shared__ int   scrI2[8][16][2];
  __shared__ float wlds[S_];
  __shared__ float shsS;
  __shared__ float rv[NTHR];

  if (bk < ND) {
    const int v0 = bk * 128;
    const int w = tx >> 6, l = tx & 63, lr = l & 15, lq = l >> 4;
    const int vr = w * 16 + lr;
    const unsigned short* brow = wobf + (size_t)(v0 + vr) * H_ + lq * 8;
    for (int bt = 0; bt < 2; ++bt) {
      const unsigned short* arow = h1bf + ((size_t)t * B_ + bt * 16 + lr) * H_ + lq * 8;
      f32x4 acc = {0.f, 0.f, 0.f, 0.f};
#pragma unroll 4
      for (int kc = 0; kc < 16; ++kc) {
        bf16x8 a = *(const bf16x8*)(arow + kc * 32);
        bf16x8 bv = *(const bf16x8*)(brow + kc * 32);
        acc = __builtin_amdgcn_mfma_f32_16x16x32_bf16(a, bv, acc, 0, 0, 0);
      }
      const float bov = p.bo[v0 + vr];
#pragma unroll
      for (int r = 0; r < 4; ++r) {
        float v1 = acc[r] + bov, v2 = -3.0e38f;
        int i1 = v0 + vr, i2 = 0x7fffffff;
        float m = v1, s = 1.0f;
#pragma unroll
        for (int d = 1; d < 16; d <<= 1) {
          float w1 = __shfl_xor(v1, d); int j1 = __shfl_xor(i1, d);
          float w2 = __shfl_xor(v2, d); int j2 = __shfl_xor(i2, d);
          float m2 = __shfl_xor(m, d);  float s2 = __shfl_xor(s, d);
          if (w1 > v1 || (w1 == v1 && j1 < i1)) { v2 = v1; i2 = i1; v1 = w1; i1 = j1; }
          else if (w1 > v2 || (w1 == v2 && j1 < i2)) { v2 = w1; i2 = j1; }
          if (w2 > v2 || (w2 == v2 && j2 < i2)) {
            if (w2 > v1 || (w2 == v1 && j2 < i1)) { v2 = v1; i2 = i1; v1 = w2; i1 = j2; }
            else { v2 = w2; i2 = j2; }
          }
          lse_merge(m, s, m2, s2);
        }
        if (lr == 0) {
          const int bb = lq * 4 + r;
          scrF[w][bb][0] = v1; scrF[w][bb][1] = v2;
          scrF[w][bb][2] = m;  scrF[w][bb][3] = s;
          scrI2[w][bb][0] = i1; scrI2[w][bb][1] = i2;
        }
      }
      __syncthreads();
      if (tx < 16) {   // combine 8 waves; publish top2 + lse partials (ALL PLAIN)
        float v1 = scrF[0][tx][0], v2 = scrF[0][tx][1];
        float m = scrF[0][tx][2], s = scrF[0][tx][3];
        int i1 = scrI2[0][tx][0], i2 = scrI2[0][tx][1];
#pragma unroll
        for (int ww = 1; ww < 8; ++ww) {
          float w1 = scrF[ww][tx][0]; int j1 = scrI2[ww][tx][0];
          float w2 = scrF[ww][tx][1]; int j2 = scrI2[ww][tx][1];
          if (w1 > v1 || (w1 == v1 && j1 < i1)) { v2 = v1; i2 = i1; v1 = w1; i1 = j1; }
          else if (w1 > v2 || (w1 == v2 && j1 < i2)) { v2 = w1; i2 = j1; }
          if (w2 > v2 || (w2 == v2 && j2 < i2)) {
            if (w2 > v1 || (w2 == v1 && j2 < i1)) { v2 = v1; i2 = i1; v1 = w2; i1 = j2; }
            else { v2 = w2; i2 = j2; }
          }
          lse_merge(m, s, scrF[ww][tx][2], scrF[ww][tx][3]);
        }
        const int b = bt * 16 + tx;
        const size_t cb = (size_t)(t * 32 + b);
        wsf[OFF_LSM + cb * 256 + bk] = m;
        wsf[OFF_LSS + cb * 256 + bk] = s;
        wsf[OFF_A2V + cb * 512 + bk * 2] = v1;
        wsf[OFF_A2V + cb * 512 + bk * 2 + 1] = v2;
        ((int*)wsf)[OFF_A2I + cb * 512 + bk * 2] = i1;
        ((int*)wsf)[OFF_A2I + cb * 512 + bk * 2 + 1] = i2;
      }
      __syncthreads();
    }
  } else if (t < T_ - 1) {       // attention for step t+1 using h1(t)
    const int q = bk - ND;
    for (int b = AST[q]; b < AST[q + 1]; ++b) {
      const float h1v = wsf[OFF_H1 + (size_t)(1 - par) * BH + (size_t)b * H_ + tx];
      rv[tx] = h1v * p.Wa[tx];
      __syncthreads();
      if (tx < 64) {
        float v = 0.f;
#pragma unroll
        for (int o = 0; o < 8; ++o) v += rv[tx + o * 64];
#pragma unroll
        for (int d = 1; d < 64; d <<= 1) v += __shfl_xor(v, d);
        if (tx == 0) shsS = v;
      }
      __syncthreads();
      if (tx < S_) {
        float sc = tanhf(shsS + wsf[OFF_CS + b * S_ + tx]);
        float e = expf(sc); float sum = e;
#pragma unroll
        for (int d = 1; d < 64; d <<= 1) sum += __shfl_xor(sum, d);
        float w2 = e / sum; wlds[tx] = w2;
        p.out[(size_t)B_ * T_ * V_ + ((size_t)b * T_ + (t + 1)) * S_ + tx] = w2;
      }
      __syncthreads();
      float a0 = 0.f;
      const float* cb = p.ctx + (size_t)b * S_ * C_ + tx;
#pragma unroll 8
      for (int s2 = 0; s2 < S_; ++s2) a0 = fmaf(wlds[s2], cb[(size_t)s2 * C_], a0);
      wsf[OFF_ATT + (size_t)b * H_ + tx] = a0;
      __syncthreads();
    }
  }
}

// ---------------- deferred LSE reduction (all t,b) ----------------
__global__ void __launch_bounds__(256) lse_all(float* __restrict__ wsf) {
  const int id = blockIdx.x, tx = threadIdx.x;   // id = t*32+b
  __shared__ float rm[256], rs[256];
  rm[tx] = (tx < ND) ? wsf[OFF_LSM + (size_t)id * 256 + tx] : -3.0e38f;
  rs[tx] = (tx < ND) ? wsf[OFF_LSS + (size_t)id * 256 + tx] : 0.f;
  __syncthreads();
  if (tx < 64) {
    float m = rm[tx], s = rs[tx];
#pragma unroll
    for (int o = 64; o < 256; o += 64) lse_merge(m, s, rm[tx + o], rs[tx + o]);
#pragma unroll
    for (int d = 1; d < 64; d <<= 1) {
      float m2 = __shfl_xor(m, d), s2 = __shfl_xor(s, d);
      lse_merge(m, s, m2, s2);
    }
    if (tx == 0) wsf[OFF_LSEA + id] = m + logf(s);
  }
}

// ---------------- final batched logp GEMM (bf16 MFMA, nt stores) ----------------
__global__ void __launch_bounds__(256) gemm_logp(const unsigned short* __restrict__ h1bf,
                                                 const unsigned short* __restrict__ wobf,
                                                 const float* __restrict__ bo,
                                                 const float* __restrict__ lsea,
                                                 float* __restrict__ out) {
  __shared__ __align__(16) unsigned short As[2][128 * 40];  // rows padded to 80B
  __shared__ __align__(16) unsigned short Bs[2][128 * 40];
  const int tx = threadIdx.x;
  const int v0 = blockIdx.x * 128, m0 = blockIdx.y * 128;
  const int w = tx >> 6, l = tx & 63;
  const int wm = w >> 1, wn = w & 1;
  f32x4 acc[4][4];
#pragma unroll
  for (int i = 0; i < 4; ++i)
#pragma unroll
    for (int j = 0; j < 4; ++j) acc[i][j] = (f32x4){0.f, 0.f, 0.f, 0.f};

#define GSTAGE(ci, kc) {                                                        \
    _Pragma("unroll")                                                           \
    for (int e = 0; e < 2; ++e) {                                               \
      const int seg = tx * 2 + e, row = seg >> 2, s = seg & 3;                  \
      *(uint4*)&As[ci][row * 40 + s * 8] =                                      \
          *(const uint4*)(h1bf + (size_t)(m0 + row) * H_ + (kc) * 32 + s * 8);  \
      *(uint4*)&Bs[ci][row * 40 + s * 8] =                                      \
          *(const uint4*)(wobf + (size_t)(v0 + row) * H_ + (kc) * 32 + s * 8);  \
    } }

  GSTAGE(0, 0);
  __syncthreads();
  for (int kc = 0; kc < 16; ++kc) {
    const int cur = kc & 1;
    if (kc < 15) GSTAGE(cur ^ 1, kc + 1);
    const int lk = (l >> 4) * 8, lr = l & 15;
    bf16x8 af[4], bf[4];
#pragma unroll
    for (int f = 0; f < 4; ++f) {
      af[f] = *(const bf16x8*)&As[cur][(wm * 64 + f * 16 + lr) * 40 + lk];
      bf[f] = *(const bf16x8*)&Bs[cur][(wn * 64 + f * 16 + lr) * 40 + lk];
    }
#pragma unroll
    for (int fm = 0; fm < 4; ++fm)
#pragma unroll
      for (int fn = 0; fn < 4; ++fn)
        acc[fm][fn] = __builtin_amdgcn_mfma_f32_16x16x32_bf16(af[fm], bf[fn], acc[fm][fn], 0, 0, 0);
    __syncthreads();
  }
#undef GSTAGE
  const int lr = l & 15, lq = l >> 4;
#pragma unroll
  for (int fm = 0; fm < 4; ++fm) {
#pragma unroll
    for (int fn = 0; fn < 4; ++fn) {
      const int v = v0 + wn * 64 + fn * 16 + lr;
      const float bov = bo[v];
#pragma unroll
      for (int r = 0; r < 4; ++r) {
        const int M = m0 + wm * 64 + fm * 16 + lq * 4 + r;
        const int tt = M >> 5, b = M & 31;
        __builtin_nontemporal_store(acc[fm][fn][r] + bov - lsea[tt * B_ + b],
                                    &out[((size_t)b * T_ + tt) * (size_t)V_ + v]);
      }
    }
  }
}

// ---------------- host launch ----------------
extern "C" void kernel_launch(void* const* d_in, const int* in_sizes, int n_in,
                              void* d_out, int out_size, void* d_ws, size_t ws_size,
                              hipStream_t stream) {
  (void)in_sizes; (void)n_in; (void)out_size;
  if (ws_size < (size_t)WS_FLOATS * sizeof(float)) return;  // workspace too small

  const float* ctx   = (const float*)d_in[0];
  // d_in[1] = max_len (scalar, == 32, hardcoded)
  const float* embed = (const float*)d_in[2];
  const float* Wa    = (const float*)d_in[3];
  const float* ba    = (const float*)d_in[4];
  const float* Wih0  = (const float*)d_in[5];
  const float* Whh0  = (const float*)d_in[6];
  const float* bih0  = (const float*)d_in[7];
  const float* bhh0  = (const float*)d_in[8];
  const float* Wih1  = (const float*)d_in[9];
  const float* Whh1  = (const float*)d_in[10];
  const float* bih1  = (const float*)d_in[11];
  const float* bhh1  = (const float*)d_in[12];
  const float* Wo    = (const float*)d_in[13];
  const float* bo    = (const float*)d_in[14];
  float* ws  = (float*)d_ws;
  float* out = (float*)d_out;

  zero_k<<<dim3(2048), dim3(256), 0, stream>>>(ws);
  cscore_k<<<dim3(32), dim3(256), 0, stream>>>(ctx, Wa, ba, ws);
  cvt_wobf<<<dim3(16000), dim3(256), 0, stream>>>(Wo, (unsigned short*)(ws + OFF_WOBF));
  attn0_k<<<dim3(32), dim3(NTHR), 0, stream>>>(ctx, ws, out);

  Params p;
  p.ctx = ctx; p.embed = embed; p.Wa = Wa;
  p.Wih0 = Wih0; p.Whh0 = Whh0; p.bih0 = bih0; p.bhh0 = bhh0;
  p.Wih1 = Wih1; p.Whh1 = Whh1; p.bih1 = bih1; p.bhh1 = bhh1;
  p.Wo = Wo; p.bo = bo; p.ws = ws; p.out = out;

  for (int t = 0; t < T_; ++t) {
    k_gru01<<<dim3(256), dim3(NTHR), 0, stream>>>(p, t);
    k_scan<<<dim3(256), dim3(NTHR), 0, stream>>>(p, t);
  }

  lse_all<<<dim3(1024), dim3(256), 0, stream>>>(ws);
  gemm_logp<<<dim3(250, 8), dim3(256), 0, stream>>>(
      (const unsigned short*)(ws + OFF_H1BF), (const unsigned short*)(ws + OFF_WOBF),
      bo, ws + OFF_LSEA, out);
}